// Round 13
// baseline (320.170 us; speedup 1.0000x reference)
//
#include <hip/hip_runtime.h>

#define NN 100000
#define NC 16
#define NE 3200000
#define NLAYERS 4
#define ALPHA_C 0.5f

#define BSHIFT 8
#define NBUK 391            // ceil(NN / 256)
#define EPB 12544           // edges per block -> exactly 256 blocks
#define NBLK 256
#define CAP 9728            // LDS staging capacity per bucket
#define PADB 1024           // per-bucket pad allowance (4-aligned segments)

typedef __attribute__((ext_vector_type(4))) _Float16 half4;
typedef __attribute__((ext_vector_type(8))) _Float16 half8;
typedef __attribute__((ext_vector_type(4))) unsigned uint4e;

static __device__ __forceinline__ unsigned short f2h_bits(float w) {
    _Float16 h = (_Float16)w;
    unsigned short b;
    __builtin_memcpy(&b, &h, 2);
    return b;
}
static __device__ __forceinline__ float hbits2f(unsigned short b) {
    _Float16 h;
    __builtin_memcpy(&h, &b, 2);
    return (float)h;
}

// ============ build phase (LDS atomics only) ============

__global__ __launch_bounds__(1024) void bucket_count(const int* __restrict__ dst,
                                                     int* __restrict__ counts) {
    __shared__ int h[NBUK];
    for (int i = threadIdx.x; i < NBUK; i += 1024) h[i] = 0;
    __syncthreads();
    int base = blockIdx.x * EPB;
    int nedge = min(EPB, NE - base);
    for (int i = threadIdx.x; i < nedge; i += 1024)
        atomicAdd(&h[dst[base + i] >> BSHIFT], 1);
    __syncthreads();
    for (int i = threadIdx.x; i < NBUK; i += 1024)
        counts[i * NBLK + blockIdx.x] = h[i];   // bucket-major for the scan
}

// Exclusive scan, 1024 elements per block (256 threads x 4 elems).
__global__ void scanA(int* __restrict__ data, int* __restrict__ blockSums, int n) {
    __shared__ int lds[256];
    int base = blockIdx.x * 1024 + threadIdx.x * 4;
    int v[4] = {0, 0, 0, 0};
#pragma unroll
    for (int i = 0; i < 4; ++i) { int idx = base + i; if (idx < n) v[i] = data[idx]; }
    int tsum = v[0] + v[1] + v[2] + v[3];
    lds[threadIdx.x] = tsum;
    __syncthreads();
    for (int off = 1; off < 256; off <<= 1) {
        int t = (threadIdx.x >= off) ? lds[threadIdx.x - off] : 0;
        __syncthreads();
        lds[threadIdx.x] += t;
        __syncthreads();
    }
    if (threadIdx.x == 255) blockSums[blockIdx.x] = lds[255];
    int run = lds[threadIdx.x] - tsum;
#pragma unroll
    for (int i = 0; i < 4; ++i) {
        int idx = base + i;
        if (idx < n) { int old = v[i]; data[idx] = run; run += old; }
    }
}

__global__ void scanB(int* __restrict__ blockSums, int nb) {
    __shared__ int lds[1024];
    int t = threadIdx.x;
    lds[t] = (t < nb) ? blockSums[t] : 0;
    __syncthreads();
    for (int off = 1; off < 1024; off <<= 1) {
        int v = (t >= off) ? lds[t - off] : 0;
        __syncthreads();
        lds[t] += v;
        __syncthreads();
    }
    if (t < nb) blockSums[t] = (t == 0) ? 0 : lds[t - 1];
}

__global__ void scanC(int* __restrict__ data, const int* __restrict__ blockSums, int n) {
    int idx = blockIdx.x * blockDim.x + threadIdx.x;
    if (idx < n) data[idx] += blockSums[idx >> 10];
    if (idx == 0) data[n] = NE;
}

// LDS-staged scatter: histogram -> LDS scan -> LDS placement (bucket-ordered)
// -> linear coalesced write-out. rec.x = src | (local_dst<<17), rec.y = w bits.
__global__ __launch_bounds__(1024) void bucket_scatter(
        const int* __restrict__ src, const int* __restrict__ dst,
        const float* __restrict__ ew, const float* __restrict__ W,
        const int* __restrict__ scanned, int2* __restrict__ recs) {
    __shared__ int2 lrec[EPB];               // 100352 B
    __shared__ unsigned short lbid[EPB];     // 25088 B
    __shared__ int h[NBUK];
    __shared__ int lbase[NBUK];
    __shared__ int delta[NBUK];
    __shared__ int sc[512];
    int t = threadIdx.x;
    int blk = blockIdx.x;
    for (int i = t; i < NBUK; i += 1024) h[i] = 0;
    __syncthreads();
    int base = blk * EPB;
    int nedge = min(EPB, NE - base);
    for (int i = t; i < nedge; i += 1024)
        atomicAdd(&h[dst[base + i] >> BSHIFT], 1);
    __syncthreads();
    // exclusive LDS scan of h -> lbase; delta = global base - local base
    if (t < 512) sc[t] = (t < NBUK) ? h[t] : 0;
    __syncthreads();
    for (int off = 1; off < 512; off <<= 1) {
        int v = (t >= off && t < 512) ? sc[t - off] : 0;
        __syncthreads();
        if (t < 512) sc[t] += v;
        __syncthreads();
    }
    if (t < NBUK) {
        int excl = sc[t] - h[t];
        lbase[t] = excl;
        delta[t] = scanned[t * NBLK + blk] - excl;
        h[t] = 0;
    }
    __syncthreads();
    // placement into LDS, bucket-ordered
    for (int i = t; i < nedge; i += 1024) {
        int e = base + i;
        int d = dst[e];
        int s = src[e];
        float w = ew[e] * W[s];
        int b = d >> BSHIFT;
        int r = atomicAdd(&h[b], 1);
        int slot = lbase[b] + r;
        lrec[slot] = make_int2(s | ((d & 255) << 17), __float_as_int(w));
        lbid[slot] = (unsigned short)b;
    }
    __syncthreads();
    // coalesced write-out: consecutive threads -> consecutive addresses per run
    for (int i = t; i < nedge; i += 1024) {
        int b = lbid[i];
        recs[i + delta[b]] = lrec[i];
    }
}

// One block (512 thr) per bucket: stage 8B records in LDS, counting-sort the
// 256 local dsts, and emit PACKED 4B records (src 17b | fp16-w 15b) with each
// node's segment PADDED to a multiple of 4 records (pads are zero = no-op
// edges). Inter-bucket gaps are zero-filled so spanning segments stay correct.
__global__ void bucket_sort(const int2* __restrict__ recs, unsigned* __restrict__ recs4,
                            const int* __restrict__ scanned, int* __restrict__ offsets) {
    __shared__ int2 lrec[CAP];
    __shared__ int hcnt[256];
    __shared__ int hscan[256];
    __shared__ int hexcl[256];
    __shared__ int hrank[256];
    int b = blockIdx.x;
    int t = threadIdx.x;
    int beg = scanned[b * NBLK];
    int end = (b == NBUK - 1) ? NE : scanned[(b + 1) * NBLK];
    int cnt = end - beg;
    int pbase = ((beg + 3) & ~3) + PADB * b;
    if (t < 256) hcnt[t] = 0;
    __syncthreads();
    for (int i = t; i < cnt && i < CAP; i += 512) {
        int2 rv = recs[beg + i];
        lrec[i] = rv;
        atomicAdd(&hcnt[(rv.x >> 17) & 255], 1);
    }
    __syncthreads();
    if (t < 256) hscan[t] = (hcnt[t] + 3) & ~3;   // padded counts
    __syncthreads();
    for (int off = 1; off < 256; off <<= 1) {
        int v = 0;
        if (t >= off && t < 256) v = hscan[t - off];
        __syncthreads();
        if (t < 256) hscan[t] += v;
        __syncthreads();
    }
    if (t < 256) {
        int pcnt = (hcnt[t] + 3) & ~3;
        hexcl[t] = hscan[t] - pcnt;               // padded exclusive prefix
        int d = (b << BSHIFT) + t;
        if (d < NN) offsets[d] = pbase + hexcl[t];
        hrank[t] = 0;
    }
    __syncthreads();
    // write real records (dst-sorted, packed)
    for (int i = t; i < cnt && i < CAP; i += 512) {
        int2 rv = lrec[i];
        int ld = (rv.x >> 17) & 255;
        int r = atomicAdd(&hrank[ld], 1);
        unsigned short hb = f2h_bits(__int_as_float(rv.y));
        recs4[pbase + hexcl[ld] + r] = (unsigned)(rv.x & 0x1FFFF) | ((unsigned)hb << 17);
    }
    __syncthreads();
    // zero per-dst pads
    if (t < 256) {
        int c = hcnt[t];
        int pc = (c + 3) & ~3;
        int o = pbase + hexcl[t];
        for (int j = c; j < pc; ++j) recs4[o + j] = 0u;
    }
    // gap-fill to next bucket's padded base (or finalize offsets[NN])
    int ptotal = hscan[255];
    int pend = pbase + ptotal;
    int nbase;
    if (b == NBUK - 1) {
        if (t == 0) offsets[NN] = pend;
        nbase = pend;
    } else {
        int nbeg = scanned[(b + 1) * NBLK];
        nbase = ((nbeg + 3) & ~3) + PADB * (b + 1);
    }
    for (int i = pend + t; i < nbase; i += 512) recs4[i] = 0u;
}

// ============ fp32 -> fp16 conversion (once, after build so it can reuse ws) ============
__global__ void f32_to_f16(const float* __restrict__ in, _Float16* __restrict__ out) {
    int i = blockIdx.x * blockDim.x + threadIdx.x;
    int base = i * 4;
    if (base < NN * NC) {
        float4 v = *reinterpret_cast<const float4*>(in + base);
        half4 o;
        o.x = (_Float16)v.x; o.y = (_Float16)v.y;
        o.z = (_Float16)v.z; o.w = (_Float16)v.w;
        *reinterpret_cast<half4*>(out + base) = o;
    }
}

// ============ per-layer gather (fp16 h, padded uint4 rec chunks, 8 lanes/node) ============
// sub = t&7: q = sub&1 owns classes [8q,8q+8); quarter = sub>>1 owns chunks
// k ≡ quarter (mod 4). One 16B rec load feeds 4 independent h loads.
// Quarters merged via shfl_xor(2,4); rownorm via shfl_xor(1).
template<bool LAST>
__global__ __launch_bounds__(256) void gather_f16(
        const _Float16* __restrict__ h, const unsigned* __restrict__ recs,
        const int* __restrict__ offsets, const float* __restrict__ degree,
        _Float16* __restrict__ hout16, float* __restrict__ hout32) {
    int t = blockIdx.x * blockDim.x + threadIdx.x;
    int g = t >> 3;
    int sub = t & 7;
    int q = sub & 1;
    int quarter = sub >> 1;
    if (g >= NN) return;
    int q8 = q * 8;
    int beg = offsets[g];          // multiple of 4
    int end = offsets[g + 1];      // multiple of 4
    int nchunk = (end - beg) >> 2;
    const uint4e* cbase = (const uint4e*)(recs + beg);
    float acc[8] = {0.f, 0.f, 0.f, 0.f, 0.f, 0.f, 0.f, 0.f};
    for (int k = quarter; k < nchunk; k += 4) {
        uint4e r = __builtin_nontemporal_load(cbase + k);
        int s0 = r[0] & 0x1FFFF, s1 = r[1] & 0x1FFFF;
        int s2 = r[2] & 0x1FFFF, s3 = r[3] & 0x1FFFF;
        const half8 h0 = *reinterpret_cast<const half8*>(h + (size_t)s0 * NC + q8);
        const half8 h1 = *reinterpret_cast<const half8*>(h + (size_t)s1 * NC + q8);
        const half8 h2 = *reinterpret_cast<const half8*>(h + (size_t)s2 * NC + q8);
        const half8 h3 = *reinterpret_cast<const half8*>(h + (size_t)s3 * NC + q8);
        float w0 = hbits2f((unsigned short)(r[0] >> 17));
        float w1 = hbits2f((unsigned short)(r[1] >> 17));
        float w2 = hbits2f((unsigned short)(r[2] >> 17));
        float w3 = hbits2f((unsigned short)(r[3] >> 17));
#pragma unroll
        for (int j = 0; j < 8; ++j) {
            acc[j] += (float)h0[j] * w0 + (float)h1[j] * w1
                    + (float)h2[j] * w2 + (float)h3[j] * w3;
        }
    }
    // merge the 4 quarters (lanes differ in bits 1-2 of sub)
#pragma unroll
    for (int j = 0; j < 8; ++j) {
        acc[j] += __shfl_xor(acc[j], 2);
        acc[j] += __shfl_xor(acc[j], 4);
    }
    float deg = degree[g];
    float d2 = deg * deg;
    const half8 hsv = *reinterpret_cast<const half8*>(h + (size_t)g * NC + q8);
    float v[8];
    float s8 = 0.f;
#pragma unroll
    for (int j = 0; j < 8; ++j) {
        v[j] = ALPHA_C * (float)hsv[j] + (1.f - ALPHA_C) * d2 * acc[j];
        s8 += v[j];
    }
    s8 += __shfl_xor(s8, 1);   // add the other class-half
    float inv = 1.f / s8;
#pragma unroll
    for (int j = 0; j < 8; ++j) v[j] *= inv;
    if (quarter == 0) {
        if (LAST) {
            float4 o0 = make_float4(v[0], v[1], v[2], v[3]);
            float4 o1 = make_float4(v[4], v[5], v[6], v[7]);
            *reinterpret_cast<float4*>(hout32 + (size_t)g * NC + q8) = o0;
            *reinterpret_cast<float4*>(hout32 + (size_t)g * NC + q8 + 4) = o1;
        } else {
            half8 o;
#pragma unroll
            for (int j = 0; j < 8; ++j) o[j] = (_Float16)v[j];
            *reinterpret_cast<half8*>(hout16 + (size_t)g * NC + q8) = o;
        }
    }
}

// ============ fallback (atomic-cursor CSR, fp32 gather) ============

__global__ void hist_kernel(const int* __restrict__ dst, int* __restrict__ counts) {
    int e = blockIdx.x * blockDim.x + threadIdx.x;
    if (e < NE) atomicAdd(&counts[dst[e]], 1);
}

__global__ void scatter_sort(const int* __restrict__ src, const int* __restrict__ dst,
                             const float* __restrict__ ew, const float* __restrict__ W,
                             const int* __restrict__ offsets, int* __restrict__ cursor,
                             int2* __restrict__ sorted) {
    int e = blockIdx.x * blockDim.x + threadIdx.x;
    if (e >= NE) return;
    int d = dst[e];
    int s = src[e];
    int pos = offsets[d] + atomicAdd(&cursor[d], 1);
    float w = ew[e] * W[s];
    sorted[pos] = make_int2(s, __float_as_int(w));
}

__global__ void gather1(const float* __restrict__ h, const int2* __restrict__ recs,
                        const int* __restrict__ offsets, const float* __restrict__ degree,
                        float* __restrict__ hout) {
    int t = blockIdx.x * blockDim.x + threadIdx.x;
    int g = t >> 2;
    int q = t & 3;
    if (g >= NN) return;
    int q4 = q * 4;
    int beg = offsets[g];
    int end = offsets[g + 1];
    float4 acc = make_float4(0.f, 0.f, 0.f, 0.f);
    for (int i = beg; i < end; ++i) {
        int2 r0 = recs[i];
        float w0 = __int_as_float(r0.y);
        const float4 h0 = *reinterpret_cast<const float4*>(h + (size_t)(r0.x & 0x1FFFF) * NC + q4);
        acc.x += h0.x * w0; acc.y += h0.y * w0; acc.z += h0.z * w0; acc.w += h0.w * w0;
    }
    float deg = degree[g];
    float d2 = deg * deg;
    const float4 hs = *reinterpret_cast<const float4*>(h + (size_t)g * NC + q4);
    float4 v;
    v.x = ALPHA_C * hs.x + (1.f - ALPHA_C) * d2 * acc.x;
    v.y = ALPHA_C * hs.y + (1.f - ALPHA_C) * d2 * acc.y;
    v.z = ALPHA_C * hs.z + (1.f - ALPHA_C) * d2 * acc.z;
    v.w = ALPHA_C * hs.w + (1.f - ALPHA_C) * d2 * acc.w;
    float s4 = v.x + v.y + v.z + v.w;
    s4 += __shfl_xor(s4, 1);
    s4 += __shfl_xor(s4, 2);
    float inv = 1.f / s4;
    v.x *= inv; v.y *= inv; v.z *= inv; v.w *= inv;
    *reinterpret_cast<float4*>(hout + (size_t)g * NC + q4) = v;
}

// ============ launch ============

extern "C" void kernel_launch(void* const* d_in, const int* in_sizes, int n_in,
                              void* d_out, int out_size, void* d_ws, size_t ws_size,
                              hipStream_t stream)
{
    const float* x      = (const float*)d_in[0];
    const float* W      = (const float*)d_in[1];
    const float* ew     = (const float*)d_in[2];
    const float* degree = (const float*)d_in[3];
    const int*   eidx   = (const int*)d_in[4];
    const int* src = eidx;
    const int* dst = eidx + NE;
    float* out = (float*)d_out;

    const int node_blocks8 = (NN * 8 + 255) / 256;     // 8 lanes per node
    const int node_blocks4 = (NN * 4 + 255) / 256;
    const int edge_blocks  = (NE + 255) / 256;

    const size_t h16_elems    = (size_t)NN * NC;               // _Float16
    const size_t unionA_bytes = (size_t)NE * 8;                // recs(int2) OR h16a+h16b (12.8MB < 25.6MB)
    const size_t recs4_elems  = (size_t)NE + (size_t)PADB * NBUK + 16;
    const size_t counts_elems = (size_t)NBUK * NBLK + 1;
    const size_t off_elems    = (size_t)NN + 1;
    const size_t need = unionA_bytes + recs4_elems * 4 + counts_elems * 4
                      + off_elems * 4 + 1024 * 4 + 64;

    if (ws_size >= need) {
        char*      u         = (char*)d_ws;
        int2*      recs      = (int2*)u;                       // build phase
        _Float16*  h16a      = (_Float16*)u;                   // gather phase (recs dead)
        _Float16*  h16b      = h16a + h16_elems;
        unsigned*  recs4     = (unsigned*)(u + unionA_bytes);
        int*       counts    = (int*)(recs4 + recs4_elems);
        int*       offsets   = counts + counts_elems;
        int*       blockSums = offsets + off_elems;

        bucket_count<<<NBLK, 1024, 0, stream>>>(dst, counts);
        const int n_scan = NBUK * NBLK;                 // 100096
        const int NB = (n_scan + 1023) / 1024;          // 98
        scanA<<<NB, 256, 0, stream>>>(counts, blockSums, n_scan);
        scanB<<<1, 1024, 0, stream>>>(blockSums, NB);
        scanC<<<(n_scan + 255) / 256, 256, 0, stream>>>(counts, blockSums, n_scan);
        bucket_scatter<<<NBLK, 1024, 0, stream>>>(src, dst, ew, W, counts, recs);
        bucket_sort<<<NBUK, 512, 0, stream>>>(recs, recs4, counts, offsets);

        f32_to_f16<<<(NN * NC / 4 + 255) / 256, 256, 0, stream>>>(x, h16a);
        gather_f16<false><<<node_blocks8, 256, 0, stream>>>(h16a, recs4, offsets, degree, h16b, nullptr);
        gather_f16<false><<<node_blocks8, 256, 0, stream>>>(h16b, recs4, offsets, degree, h16a, nullptr);
        gather_f16<false><<<node_blocks8, 256, 0, stream>>>(h16a, recs4, offsets, degree, h16b, nullptr);
        gather_f16<true ><<<node_blocks8, 256, 0, stream>>>(h16b, recs4, offsets, degree, nullptr, out);
        return;
    }

    // -------- fallback: single CSR with cursor atomics, fp32 gather --------
    {
        const size_t bufA_elems = (size_t)NN * NC;
        int2*  sorted    = (int2*)d_ws;
        float* bufA      = (float*)(sorted + NE);
        int*   offsets   = (int*)(bufA + bufA_elems);
        int*   cursor    = offsets + (NN + 1);
        int*   blockSums = cursor + NN;

        (void)hipMemsetAsync(offsets, 0, (size_t)(2 * NN + 1) * sizeof(int), stream);
        hist_kernel<<<edge_blocks, 256, 0, stream>>>(dst, offsets);
        const int NB = (NN + 1023) / 1024;
        scanA<<<NB, 256, 0, stream>>>(offsets, blockSums, NN);
        scanB<<<1, 1024, 0, stream>>>(blockSums, NB);
        scanC<<<(NN + 255) / 256, 256, 0, stream>>>(offsets, blockSums, NN);
        scatter_sort<<<edge_blocks, 256, 0, stream>>>(src, dst, ew, W, offsets, cursor, sorted);

        const float* hin = x;
        float* houts[NLAYERS] = {bufA, out, bufA, out};
        for (int l = 0; l < NLAYERS; ++l) {
            gather1<<<node_blocks4, 256, 0, stream>>>(hin, sorted, offsets, degree, houts[l]);
            hin = houts[l];
        }
    }
}

// Round 14
// 235.079 us; speedup vs baseline: 1.3620x; 1.3620x over previous
//
#include <hip/hip_runtime.h>

#define NN 100000
#define NC 16
#define NE 3200000
#define NLAYERS 4
#define ALPHA_C 0.5f

#define BSHIFT 8
#define NBUK 391            // ceil(NN / 256)
#define EPB 12544           // edges per block -> exactly 256 blocks
#define NBLK 256
#define CAP 9728            // LDS staging capacity per bucket
#define NBLK2 391           // node blocks for degree counting-sort (256 nodes each)

typedef __attribute__((ext_vector_type(4))) _Float16 half4;
typedef __attribute__((ext_vector_type(8))) _Float16 half8;

static __device__ __forceinline__ unsigned short f2h_bits(float w) {
    _Float16 h = (_Float16)w;
    unsigned short b;
    __builtin_memcpy(&b, &h, 2);
    return b;
}
static __device__ __forceinline__ float hbits2f(unsigned short b) {
    _Float16 h;
    __builtin_memcpy(&h, &b, 2);
    return (float)h;
}

// ============ build phase (LDS atomics only) ============

__global__ __launch_bounds__(1024) void bucket_count(const int* __restrict__ dst,
                                                     int* __restrict__ counts) {
    __shared__ int h[NBUK];
    for (int i = threadIdx.x; i < NBUK; i += 1024) h[i] = 0;
    __syncthreads();
    int base = blockIdx.x * EPB;
    int nedge = min(EPB, NE - base);
    for (int i = threadIdx.x; i < nedge; i += 1024)
        atomicAdd(&h[dst[base + i] >> BSHIFT], 1);
    __syncthreads();
    for (int i = threadIdx.x; i < NBUK; i += 1024)
        counts[i * NBLK + blockIdx.x] = h[i];   // bucket-major for the scan
}

// Exclusive scan, 1024 elements per block (256 threads x 4 elems).
__global__ void scanA(int* __restrict__ data, int* __restrict__ blockSums, int n) {
    __shared__ int lds[256];
    int base = blockIdx.x * 1024 + threadIdx.x * 4;
    int v[4] = {0, 0, 0, 0};
#pragma unroll
    for (int i = 0; i < 4; ++i) { int idx = base + i; if (idx < n) v[i] = data[idx]; }
    int tsum = v[0] + v[1] + v[2] + v[3];
    lds[threadIdx.x] = tsum;
    __syncthreads();
    for (int off = 1; off < 256; off <<= 1) {
        int t = (threadIdx.x >= off) ? lds[threadIdx.x - off] : 0;
        __syncthreads();
        lds[threadIdx.x] += t;
        __syncthreads();
    }
    if (threadIdx.x == 255) blockSums[blockIdx.x] = lds[255];
    int run = lds[threadIdx.x] - tsum;
#pragma unroll
    for (int i = 0; i < 4; ++i) {
        int idx = base + i;
        if (idx < n) { int old = v[i]; data[idx] = run; run += old; }
    }
}

__global__ void scanB(int* __restrict__ blockSums, int nb) {
    __shared__ int lds[1024];
    int t = threadIdx.x;
    lds[t] = (t < nb) ? blockSums[t] : 0;
    __syncthreads();
    for (int off = 1; off < 1024; off <<= 1) {
        int v = (t >= off) ? lds[t - off] : 0;
        __syncthreads();
        lds[t] += v;
        __syncthreads();
    }
    if (t < nb) blockSums[t] = (t == 0) ? 0 : lds[t - 1];
}

__global__ void scanC(int* __restrict__ data, const int* __restrict__ blockSums, int n) {
    int idx = blockIdx.x * blockDim.x + threadIdx.x;
    if (idx < n) data[idx] += blockSums[idx >> 10];
    if (idx == 0) data[n] = NE;
}

// LDS-staged scatter: histogram -> LDS scan -> LDS placement (bucket-ordered)
// -> linear coalesced write-out. rec.x = src | (local_dst<<17), rec.y = w bits.
__global__ __launch_bounds__(1024) void bucket_scatter(
        const int* __restrict__ src, const int* __restrict__ dst,
        const float* __restrict__ ew, const float* __restrict__ W,
        const int* __restrict__ scanned, int2* __restrict__ recs) {
    __shared__ int2 lrec[EPB];               // 100352 B
    __shared__ unsigned short lbid[EPB];     // 25088 B
    __shared__ int h[NBUK];
    __shared__ int lbase[NBUK];
    __shared__ int delta[NBUK];
    __shared__ int sc[512];
    int t = threadIdx.x;
    int blk = blockIdx.x;
    for (int i = t; i < NBUK; i += 1024) h[i] = 0;
    __syncthreads();
    int base = blk * EPB;
    int nedge = min(EPB, NE - base);
    for (int i = t; i < nedge; i += 1024)
        atomicAdd(&h[dst[base + i] >> BSHIFT], 1);
    __syncthreads();
    // exclusive LDS scan of h -> lbase; delta = global base - local base
    if (t < 512) sc[t] = (t < NBUK) ? h[t] : 0;
    __syncthreads();
    for (int off = 1; off < 512; off <<= 1) {
        int v = (t >= off && t < 512) ? sc[t - off] : 0;
        __syncthreads();
        if (t < 512) sc[t] += v;
        __syncthreads();
    }
    if (t < NBUK) {
        int excl = sc[t] - h[t];
        lbase[t] = excl;
        delta[t] = scanned[t * NBLK + blk] - excl;
        h[t] = 0;
    }
    __syncthreads();
    // placement into LDS, bucket-ordered
    for (int i = t; i < nedge; i += 1024) {
        int e = base + i;
        int d = dst[e];
        int s = src[e];
        float w = ew[e] * W[s];
        int b = d >> BSHIFT;
        int r = atomicAdd(&h[b], 1);
        int slot = lbase[b] + r;
        lrec[slot] = make_int2(s | ((d & 255) << 17), __float_as_int(w));
        lbid[slot] = (unsigned short)b;
    }
    __syncthreads();
    // coalesced write-out: consecutive threads -> consecutive addresses per run
    for (int i = t; i < nedge; i += 1024) {
        int b = lbid[i];
        recs[i + delta[b]] = lrec[i];
    }
}

// One block (512 thr) per bucket: stage 8B records in LDS, counting-sort the
// 256 local dsts, write CSR offsets, and emit PACKED 4B records
// (src 17b | fp16-w-no-sign 15b), fully dst-sorted.
__global__ void bucket_sort(const int2* __restrict__ recs, unsigned* __restrict__ recs4,
                            const int* __restrict__ scanned, int* __restrict__ offsets) {
    __shared__ int2 lrec[CAP];
    __shared__ int hcnt[256];
    __shared__ int hscan[256];
    __shared__ int hexcl[256];
    int b = blockIdx.x;
    int t = threadIdx.x;
    int beg = scanned[b * NBLK];
    int end = (b == NBUK - 1) ? NE : scanned[(b + 1) * NBLK];
    int cnt = end - beg;
    if (t < 256) hcnt[t] = 0;
    __syncthreads();
    for (int i = t; i < cnt && i < CAP; i += 512) {
        int2 rv = recs[beg + i];
        lrec[i] = rv;
        atomicAdd(&hcnt[(rv.x >> 17) & 255], 1);
    }
    __syncthreads();
    if (t < 256) hscan[t] = hcnt[t];
    __syncthreads();
    for (int off = 1; off < 256; off <<= 1) {
        int v = 0;
        if (t >= off && t < 256) v = hscan[t - off];
        __syncthreads();
        if (t < 256) hscan[t] += v;
        __syncthreads();
    }
    if (t < 256) {
        hexcl[t] = hscan[t] - hcnt[t];
        int d = (b << BSHIFT) + t;
        if (d < NN) offsets[d] = beg + hexcl[t];
        hcnt[t] = 0;
    }
    if (b == NBUK - 1 && t == 0) offsets[NN] = NE;
    __syncthreads();
    for (int i = t; i < cnt && i < CAP; i += 512) {
        int2 rv = lrec[i];
        int ld = (rv.x >> 17) & 255;
        int r = atomicAdd(&hcnt[ld], 1);
        unsigned short hb = f2h_bits(__int_as_float(rv.y));
        recs4[beg + hexcl[ld] + r] = (unsigned)(rv.x & 0x1FFFF) | ((unsigned)hb << 17);
    }
}

// ============ degree-sorted node permutation (counting sort, LDS atomics) ============

__global__ __launch_bounds__(256) void deg_count(const int* __restrict__ offsets,
                                                 int* __restrict__ dcounts) {
    __shared__ int h[256];
    h[threadIdx.x] = 0;
    __syncthreads();
    int g = blockIdx.x * 256 + threadIdx.x;
    if (g < NN) {
        int deg = min(offsets[g + 1] - offsets[g], 255);
        atomicAdd(&h[deg], 1);
    }
    __syncthreads();
    dcounts[threadIdx.x * NBLK2 + blockIdx.x] = h[threadIdx.x];  // bin-major
}

__global__ __launch_bounds__(256) void perm_scatter(const int* __restrict__ offsets,
                                                    const int* __restrict__ dscanned,
                                                    int* __restrict__ perm) {
    __shared__ int h[256];
    __shared__ int basep[256];
    h[threadIdx.x] = 0;
    basep[threadIdx.x] = dscanned[threadIdx.x * NBLK2 + blockIdx.x];
    __syncthreads();
    int g = blockIdx.x * 256 + threadIdx.x;
    if (g < NN) {
        int deg = min(offsets[g + 1] - offsets[g], 255);
        int r = atomicAdd(&h[deg], 1);
        perm[basep[deg] + r] = g;
    }
}

// ============ fp32 -> fp16 conversion (once) ============
__global__ void f32_to_f16(const float* __restrict__ in, _Float16* __restrict__ out) {
    int i = blockIdx.x * blockDim.x + threadIdx.x;
    int base = i * 4;
    if (base < NN * NC) {
        float4 v = *reinterpret_cast<const float4*>(in + base);
        half4 o;
        o.x = (_Float16)v.x; o.y = (_Float16)v.y;
        o.z = (_Float16)v.z; o.w = (_Float16)v.w;
        *reinterpret_cast<half4*>(out + base) = o;
    }
}

// ============ per-layer gather (fp16 h, packed 4B recs, 8 lanes/node,
//              degree-sorted node order via perm) ============
// sub = t&7: q = sub&1 owns classes [8q,8q+8); quarter = sub>>1 owns an edge
// quarter. Quarters merged via shfl_xor(2,4); rownorm via shfl_xor(1).
template<bool LAST>
__global__ __launch_bounds__(256) void gather_f16(
        const _Float16* __restrict__ h, const unsigned* __restrict__ recs,
        const int* __restrict__ offsets, const int* __restrict__ perm,
        const float* __restrict__ degree,
        _Float16* __restrict__ hout16, float* __restrict__ hout32) {
    int t = blockIdx.x * blockDim.x + threadIdx.x;
    int grp = t >> 3;
    int sub = t & 7;
    int q = sub & 1;
    int quarter = sub >> 1;
    if (grp >= NN) return;
    int g = perm[grp];
    int q8 = q * 8;
    int beg = offsets[g];
    int end = offsets[g + 1];
    int len = end - beg;
    int qlen = (len + 3) >> 2;
    int lo = beg + quarter * qlen;
    int hi = lo + qlen;
    if (lo > end) lo = end;
    if (hi > end) hi = end;
    float acc[8] = {0.f, 0.f, 0.f, 0.f, 0.f, 0.f, 0.f, 0.f};
    int i = lo;
    for (; i + 4 <= hi; i += 4) {
        unsigned r0 = __builtin_nontemporal_load(recs + i);
        unsigned r1 = __builtin_nontemporal_load(recs + i + 1);
        unsigned r2 = __builtin_nontemporal_load(recs + i + 2);
        unsigned r3 = __builtin_nontemporal_load(recs + i + 3);
        int s0 = r0 & 0x1FFFF, s1 = r1 & 0x1FFFF, s2 = r2 & 0x1FFFF, s3 = r3 & 0x1FFFF;
        const half8 h0 = *reinterpret_cast<const half8*>(h + (size_t)s0 * NC + q8);
        const half8 h1 = *reinterpret_cast<const half8*>(h + (size_t)s1 * NC + q8);
        const half8 h2 = *reinterpret_cast<const half8*>(h + (size_t)s2 * NC + q8);
        const half8 h3 = *reinterpret_cast<const half8*>(h + (size_t)s3 * NC + q8);
        float w0 = hbits2f((unsigned short)(r0 >> 17));
        float w1 = hbits2f((unsigned short)(r1 >> 17));
        float w2 = hbits2f((unsigned short)(r2 >> 17));
        float w3 = hbits2f((unsigned short)(r3 >> 17));
#pragma unroll
        for (int j = 0; j < 8; ++j) {
            acc[j] += (float)h0[j] * w0 + (float)h1[j] * w1
                    + (float)h2[j] * w2 + (float)h3[j] * w3;
        }
    }
    for (; i < hi; ++i) {
        unsigned r0 = __builtin_nontemporal_load(recs + i);
        int s0 = r0 & 0x1FFFF;
        float w0 = hbits2f((unsigned short)(r0 >> 17));
        const half8 h0 = *reinterpret_cast<const half8*>(h + (size_t)s0 * NC + q8);
#pragma unroll
        for (int j = 0; j < 8; ++j) acc[j] += (float)h0[j] * w0;
    }
    // merge the 4 edge-quarters (lanes differ in bits 1-2 of sub)
#pragma unroll
    for (int j = 0; j < 8; ++j) {
        acc[j] += __shfl_xor(acc[j], 2);
        acc[j] += __shfl_xor(acc[j], 4);
    }
    float deg = degree[g];
    float d2 = deg * deg;
    const half8 hsv = *reinterpret_cast<const half8*>(h + (size_t)g * NC + q8);
    float v[8];
    float s8 = 0.f;
#pragma unroll
    for (int j = 0; j < 8; ++j) {
        v[j] = ALPHA_C * (float)hsv[j] + (1.f - ALPHA_C) * d2 * acc[j];
        s8 += v[j];
    }
    s8 += __shfl_xor(s8, 1);   // add the other class-half
    float inv = 1.f / s8;
#pragma unroll
    for (int j = 0; j < 8; ++j) v[j] *= inv;
    if (quarter == 0) {
        if (LAST) {
            float4 o0 = make_float4(v[0], v[1], v[2], v[3]);
            float4 o1 = make_float4(v[4], v[5], v[6], v[7]);
            *reinterpret_cast<float4*>(hout32 + (size_t)g * NC + q8) = o0;
            *reinterpret_cast<float4*>(hout32 + (size_t)g * NC + q8 + 4) = o1;
        } else {
            half8 o;
#pragma unroll
            for (int j = 0; j < 8; ++j) o[j] = (_Float16)v[j];
            *reinterpret_cast<half8*>(hout16 + (size_t)g * NC + q8) = o;
        }
    }
}

// ============ fallback (atomic-cursor CSR, fp32 gather) ============

__global__ void hist_kernel(const int* __restrict__ dst, int* __restrict__ counts) {
    int e = blockIdx.x * blockDim.x + threadIdx.x;
    if (e < NE) atomicAdd(&counts[dst[e]], 1);
}

__global__ void scatter_sort(const int* __restrict__ src, const int* __restrict__ dst,
                             const float* __restrict__ ew, const float* __restrict__ W,
                             const int* __restrict__ offsets, int* __restrict__ cursor,
                             int2* __restrict__ sorted) {
    int e = blockIdx.x * blockDim.x + threadIdx.x;
    if (e >= NE) return;
    int d = dst[e];
    int s = src[e];
    int pos = offsets[d] + atomicAdd(&cursor[d], 1);
    float w = ew[e] * W[s];
    sorted[pos] = make_int2(s, __float_as_int(w));
}

__global__ void gather1(const float* __restrict__ h, const int2* __restrict__ recs,
                        const int* __restrict__ offsets, const float* __restrict__ degree,
                        float* __restrict__ hout) {
    int t = blockIdx.x * blockDim.x + threadIdx.x;
    int g = t >> 2;
    int q = t & 3;
    if (g >= NN) return;
    int q4 = q * 4;
    int beg = offsets[g];
    int end = offsets[g + 1];
    float4 acc = make_float4(0.f, 0.f, 0.f, 0.f);
    for (int i = beg; i < end; ++i) {
        int2 r0 = recs[i];
        float w0 = __int_as_float(r0.y);
        const float4 h0 = *reinterpret_cast<const float4*>(h + (size_t)(r0.x & 0x1FFFF) * NC + q4);
        acc.x += h0.x * w0; acc.y += h0.y * w0; acc.z += h0.z * w0; acc.w += h0.w * w0;
    }
    float deg = degree[g];
    float d2 = deg * deg;
    const float4 hs = *reinterpret_cast<const float4*>(h + (size_t)g * NC + q4);
    float4 v;
    v.x = ALPHA_C * hs.x + (1.f - ALPHA_C) * d2 * acc.x;
    v.y = ALPHA_C * hs.y + (1.f - ALPHA_C) * d2 * acc.y;
    v.z = ALPHA_C * hs.z + (1.f - ALPHA_C) * d2 * acc.z;
    v.w = ALPHA_C * hs.w + (1.f - ALPHA_C) * d2 * acc.w;
    float s4 = v.x + v.y + v.z + v.w;
    s4 += __shfl_xor(s4, 1);
    s4 += __shfl_xor(s4, 2);
    float inv = 1.f / s4;
    v.x *= inv; v.y *= inv; v.z *= inv; v.w *= inv;
    *reinterpret_cast<float4*>(hout + (size_t)g * NC + q4) = v;
}

// ============ launch ============

extern "C" void kernel_launch(void* const* d_in, const int* in_sizes, int n_in,
                              void* d_out, int out_size, void* d_ws, size_t ws_size,
                              hipStream_t stream)
{
    const float* x      = (const float*)d_in[0];
    const float* W      = (const float*)d_in[1];
    const float* ew     = (const float*)d_in[2];
    const float* degree = (const float*)d_in[3];
    const int*   eidx   = (const int*)d_in[4];
    const int* src = eidx;
    const int* dst = eidx + NE;
    float* out = (float*)d_out;

    const int node_blocks8 = (NN * 8 + 255) / 256;     // 8 lanes per node
    const int node_blocks4 = (NN * 4 + 255) / 256;
    const int edge_blocks  = (NE + 255) / 256;

    const size_t h16_elems    = (size_t)NN * NC;               // _Float16
    const size_t unionA_bytes = (size_t)NE * 8;                // recs(int2) OR h16a+h16b
    const size_t recs4_elems  = (size_t)NE;
    const size_t counts_elems = (size_t)NBUK * NBLK + 1;       // 100097
    const size_t dcnt_elems   = (size_t)256 * NBLK2 + 1;       // 100097
    const size_t off_elems    = (size_t)NN + 1;
    const size_t need = unionA_bytes + recs4_elems * 4 + counts_elems * 4
                      + dcnt_elems * 4 + off_elems * 4 + (size_t)NN * 4
                      + 1024 * 4 + 64;

    if (ws_size >= need) {
        char*      u         = (char*)d_ws;
        int2*      recs      = (int2*)u;                       // build phase
        _Float16*  h16a      = (_Float16*)u;                   // gather phase (recs dead)
        _Float16*  h16b      = h16a + h16_elems;
        unsigned*  recs4     = (unsigned*)(u + unionA_bytes);
        int*       counts    = (int*)(recs4 + recs4_elems);
        int*       dcounts   = counts + counts_elems;
        int*       offsets   = dcounts + dcnt_elems;
        int*       perm      = offsets + off_elems;
        int*       blockSums = perm + NN;

        bucket_count<<<NBLK, 1024, 0, stream>>>(dst, counts);
        const int n_scan = NBUK * NBLK;                 // 100096
        const int NB = (n_scan + 1023) / 1024;          // 98
        scanA<<<NB, 256, 0, stream>>>(counts, blockSums, n_scan);
        scanB<<<1, 1024, 0, stream>>>(blockSums, NB);
        scanC<<<(n_scan + 255) / 256, 256, 0, stream>>>(counts, blockSums, n_scan);
        bucket_scatter<<<NBLK, 1024, 0, stream>>>(src, dst, ew, W, counts, recs);
        bucket_sort<<<NBUK, 512, 0, stream>>>(recs, recs4, counts, offsets);

        // degree-sorted node permutation (counting sort over 256 degree bins)
        deg_count<<<NBLK2, 256, 0, stream>>>(offsets, dcounts);
        const int n_scan2 = 256 * NBLK2;                // 100096
        const int NB2 = (n_scan2 + 1023) / 1024;        // 98
        scanA<<<NB2, 256, 0, stream>>>(dcounts, blockSums, n_scan2);
        scanB<<<1, 1024, 0, stream>>>(blockSums, NB2);
        scanC<<<(n_scan2 + 255) / 256, 256, 0, stream>>>(dcounts, blockSums, n_scan2);
        perm_scatter<<<NBLK2, 256, 0, stream>>>(offsets, dcounts, perm);

        f32_to_f16<<<(NN * NC / 4 + 255) / 256, 256, 0, stream>>>(x, h16a);
        gather_f16<false><<<node_blocks8, 256, 0, stream>>>(h16a, recs4, offsets, perm, degree, h16b, nullptr);
        gather_f16<false><<<node_blocks8, 256, 0, stream>>>(h16b, recs4, offsets, perm, degree, h16a, nullptr);
        gather_f16<false><<<node_blocks8, 256, 0, stream>>>(h16a, recs4, offsets, perm, degree, h16b, nullptr);
        gather_f16<true ><<<node_blocks8, 256, 0, stream>>>(h16b, recs4, offsets, perm, degree, nullptr, out);
        return;
    }

    // -------- fallback: single CSR with cursor atomics, fp32 gather --------
    {
        const size_t bufA_elems = (size_t)NN * NC;
        int2*  sorted    = (int2*)d_ws;
        float* bufA      = (float*)(sorted + NE);
        int*   offsets   = (int*)(bufA + bufA_elems);
        int*   cursor    = offsets + (NN + 1);
        int*   blockSums = cursor + NN;

        (void)hipMemsetAsync(offsets, 0, (size_t)(2 * NN + 1) * sizeof(int), stream);
        hist_kernel<<<edge_blocks, 256, 0, stream>>>(dst, offsets);
        const int NB = (NN + 1023) / 1024;
        scanA<<<NB, 256, 0, stream>>>(offsets, blockSums, NN);
        scanB<<<1, 1024, 0, stream>>>(blockSums, NB);
        scanC<<<(NN + 255) / 256, 256, 0, stream>>>(offsets, blockSums, NN);
        scatter_sort<<<edge_blocks, 256, 0, stream>>>(src, dst, ew, W, offsets, cursor, sorted);

        const float* hin = x;
        float* houts[NLAYERS] = {bufA, out, bufA, out};
        for (int l = 0; l < NLAYERS; ++l) {
            gather1<<<node_blocks4, 256, 0, stream>>>(hin, sorted, offsets, degree, houts[l]);
            hin = houts[l];
        }
    }
}

// Round 15
// 229.233 us; speedup vs baseline: 1.3967x; 1.0255x over previous
//
#include <hip/hip_runtime.h>

#define NN 100000
#define NC 16
#define NE 3200000
#define NLAYERS 4
#define ALPHA_C 0.5f

#define BSHIFT 8
#define NBUK 391            // ceil(NN / 256)
#define EPB 12544           // edges per block -> exactly 256 blocks
#define NBLK 256
#define CAP 9728            // LDS staging capacity per bucket (mean 8192, +17 sigma)

typedef __attribute__((ext_vector_type(4))) _Float16 half4;
typedef __attribute__((ext_vector_type(8))) _Float16 half8;

static __device__ __forceinline__ unsigned short f2h_bits(float w) {
    _Float16 h = (_Float16)w;
    unsigned short b;
    __builtin_memcpy(&b, &h, 2);
    return b;
}
static __device__ __forceinline__ float hbits2f(unsigned short b) {
    _Float16 h;
    __builtin_memcpy(&h, &b, 2);
    return (float)h;
}

// ============ build phase (LDS atomics only) ============

__global__ __launch_bounds__(1024) void bucket_count(const int* __restrict__ dst,
                                                     int* __restrict__ counts) {
    __shared__ int h[NBUK];
    for (int i = threadIdx.x; i < NBUK; i += 1024) h[i] = 0;
    __syncthreads();
    int base = blockIdx.x * EPB;
    int nedge = min(EPB, NE - base);
    for (int i = threadIdx.x; i < nedge; i += 1024)
        atomicAdd(&h[dst[base + i] >> BSHIFT], 1);
    __syncthreads();
    for (int i = threadIdx.x; i < NBUK; i += 1024)
        counts[i * NBLK + blockIdx.x] = h[i];   // bucket-major for the scan
}

// Exclusive scan, 1024 elements per block (256 threads x 4 elems).
__global__ void scanA(int* __restrict__ data, int* __restrict__ blockSums, int n) {
    __shared__ int lds[256];
    int base = blockIdx.x * 1024 + threadIdx.x * 4;
    int v[4] = {0, 0, 0, 0};
#pragma unroll
    for (int i = 0; i < 4; ++i) { int idx = base + i; if (idx < n) v[i] = data[idx]; }
    int tsum = v[0] + v[1] + v[2] + v[3];
    lds[threadIdx.x] = tsum;
    __syncthreads();
    for (int off = 1; off < 256; off <<= 1) {
        int t = (threadIdx.x >= off) ? lds[threadIdx.x - off] : 0;
        __syncthreads();
        lds[threadIdx.x] += t;
        __syncthreads();
    }
    if (threadIdx.x == 255) blockSums[blockIdx.x] = lds[255];
    int run = lds[threadIdx.x] - tsum;
#pragma unroll
    for (int i = 0; i < 4; ++i) {
        int idx = base + i;
        if (idx < n) { int old = v[i]; data[idx] = run; run += old; }
    }
}

__global__ void scanB(int* __restrict__ blockSums, int nb) {
    __shared__ int lds[1024];
    int t = threadIdx.x;
    lds[t] = (t < nb) ? blockSums[t] : 0;
    __syncthreads();
    for (int off = 1; off < 1024; off <<= 1) {
        int v = (t >= off) ? lds[t - off] : 0;
        __syncthreads();
        lds[t] += v;
        __syncthreads();
    }
    if (t < nb) blockSums[t] = (t == 0) ? 0 : lds[t - 1];
}

__global__ void scanC(int* __restrict__ data, const int* __restrict__ blockSums, int n) {
    int idx = blockIdx.x * blockDim.x + threadIdx.x;
    if (idx < n) data[idx] += blockSums[idx >> 10];
    if (idx == 0) data[n] = NE;
}

// LDS-staged scatter: histogram -> LDS scan -> LDS placement (bucket-ordered)
// -> linear coalesced write-out. rec.x = src | (local_dst<<17), rec.y = w bits.
__global__ __launch_bounds__(1024) void bucket_scatter(
        const int* __restrict__ src, const int* __restrict__ dst,
        const float* __restrict__ ew, const float* __restrict__ W,
        const int* __restrict__ scanned, int2* __restrict__ recs) {
    __shared__ int2 lrec[EPB];               // 100352 B
    __shared__ unsigned short lbid[EPB];     // 25088 B
    __shared__ int h[NBUK];
    __shared__ int lbase[NBUK];
    __shared__ int delta[NBUK];
    __shared__ int sc[512];
    int t = threadIdx.x;
    int blk = blockIdx.x;
    for (int i = t; i < NBUK; i += 1024) h[i] = 0;
    __syncthreads();
    int base = blk * EPB;
    int nedge = min(EPB, NE - base);
    for (int i = t; i < nedge; i += 1024)
        atomicAdd(&h[dst[base + i] >> BSHIFT], 1);
    __syncthreads();
    // exclusive LDS scan of h -> lbase; delta = global base - local base
    if (t < 512) sc[t] = (t < NBUK) ? h[t] : 0;
    __syncthreads();
    for (int off = 1; off < 512; off <<= 1) {
        int v = (t >= off && t < 512) ? sc[t - off] : 0;
        __syncthreads();
        if (t < 512) sc[t] += v;
        __syncthreads();
    }
    if (t < NBUK) {
        int excl = sc[t] - h[t];
        lbase[t] = excl;
        delta[t] = scanned[t * NBLK + blk] - excl;
        h[t] = 0;
    }
    __syncthreads();
    // placement into LDS, bucket-ordered
    for (int i = t; i < nedge; i += 1024) {
        int e = base + i;
        int d = dst[e];
        int s = src[e];
        float w = ew[e] * W[s];
        int b = d >> BSHIFT;
        int r = atomicAdd(&h[b], 1);
        int slot = lbase[b] + r;
        lrec[slot] = make_int2(s | ((d & 255) << 17), __float_as_int(w));
        lbid[slot] = (unsigned short)b;
    }
    __syncthreads();
    // coalesced write-out: consecutive threads -> consecutive addresses per run
    for (int i = t; i < nedge; i += 1024) {
        int b = lbid[i];
        recs[i + delta[b]] = lrec[i];
    }
}

// One block (512 thr) per bucket: stage 8B records in LDS, counting-sort the
// 256 local dsts, write CSR offsets, and emit PACKED 4B records
// (src 17b | fp16-w-no-sign 15b), fully dst-sorted.
__global__ void bucket_sort(const int2* __restrict__ recs, unsigned* __restrict__ recs4,
                            const int* __restrict__ scanned, int* __restrict__ offsets) {
    __shared__ int2 lrec[CAP];
    __shared__ int hcnt[256];
    __shared__ int hscan[256];
    __shared__ int hexcl[256];
    int b = blockIdx.x;
    int t = threadIdx.x;
    int beg = scanned[b * NBLK];
    int end = (b == NBUK - 1) ? NE : scanned[(b + 1) * NBLK];
    int cnt = end - beg;
    if (t < 256) hcnt[t] = 0;
    __syncthreads();
    for (int i = t; i < cnt && i < CAP; i += 512) {
        int2 rv = recs[beg + i];
        lrec[i] = rv;
        atomicAdd(&hcnt[(rv.x >> 17) & 255], 1);
    }
    __syncthreads();
    if (t < 256) hscan[t] = hcnt[t];
    __syncthreads();
    for (int off = 1; off < 256; off <<= 1) {
        int v = 0;
        if (t >= off && t < 256) v = hscan[t - off];
        __syncthreads();
        if (t < 256) hscan[t] += v;
        __syncthreads();
    }
    if (t < 256) {
        hexcl[t] = hscan[t] - hcnt[t];
        int d = (b << BSHIFT) + t;
        if (d < NN) offsets[d] = beg + hexcl[t];
        hcnt[t] = 0;
    }
    if (b == NBUK - 1 && t == 0) offsets[NN] = NE;
    __syncthreads();
    for (int i = t; i < cnt && i < CAP; i += 512) {
        int2 rv = lrec[i];
        int ld = (rv.x >> 17) & 255;
        int r = atomicAdd(&hcnt[ld], 1);
        unsigned short hb = f2h_bits(__int_as_float(rv.y));
        recs4[beg + hexcl[ld] + r] = (unsigned)(rv.x & 0x1FFFF) | ((unsigned)hb << 17);
    }
}

// ============ fp32 -> fp16 conversion (once) ============
__global__ void f32_to_f16(const float* __restrict__ in, _Float16* __restrict__ out) {
    int i = blockIdx.x * blockDim.x + threadIdx.x;
    int base = i * 4;
    if (base < NN * NC) {
        float4 v = *reinterpret_cast<const float4*>(in + base);
        half4 o;
        o.x = (_Float16)v.x; o.y = (_Float16)v.y;
        o.z = (_Float16)v.z; o.w = (_Float16)v.w;
        *reinterpret_cast<half4*>(out + base) = o;
    }
}

// ============ per-layer gather (fp16 h, packed 4B recs, 8 lanes/node) ============
// sub = t&7: q = sub&1 owns classes [8q,8q+8); quarter = sub>>1 owns an edge
// quarter. Rec loads are SPLIT between the two class-half lanes (q=0 loads
// recs i,i+1; q=1 loads i+2,i+3) and exchanged via shfl_xor(1) — halves the
// rec VMEM instruction count. Sum order per lane differs; sums are assoc-free.
// Quarters merged via shfl_xor(2,4); rownorm via shfl_xor(1).
template<bool LAST>
__global__ __launch_bounds__(256) void gather_f16(
        const _Float16* __restrict__ h, const unsigned* __restrict__ recs,
        const int* __restrict__ offsets, const float* __restrict__ degree,
        _Float16* __restrict__ hout16, float* __restrict__ hout32) {
    int t = blockIdx.x * blockDim.x + threadIdx.x;
    int g = t >> 3;
    int sub = t & 7;
    int q = sub & 1;
    int quarter = sub >> 1;
    if (g >= NN) return;
    int q8 = q * 8;
    int beg = offsets[g];
    int end = offsets[g + 1];
    int len = end - beg;
    int qlen = (len + 3) >> 2;
    int lo = beg + quarter * qlen;
    int hi = lo + qlen;
    if (lo > end) lo = end;
    if (hi > end) hi = end;
    float acc[8] = {0.f, 0.f, 0.f, 0.f, 0.f, 0.f, 0.f, 0.f};
    int i = lo;
    for (; i + 4 <= hi; i += 4) {
        // split rec loads across the class-half pair, exchange via shfl
        unsigned ra = __builtin_nontemporal_load(recs + i + 2 * q);
        unsigned rb = __builtin_nontemporal_load(recs + i + 2 * q + 1);
        unsigned rc = (unsigned)__shfl_xor((int)ra, 1);
        unsigned rd = (unsigned)__shfl_xor((int)rb, 1);
        int s0 = ra & 0x1FFFF, s1 = rb & 0x1FFFF, s2 = rc & 0x1FFFF, s3 = rd & 0x1FFFF;
        const half8 h0 = *reinterpret_cast<const half8*>(h + (size_t)s0 * NC + q8);
        const half8 h1 = *reinterpret_cast<const half8*>(h + (size_t)s1 * NC + q8);
        const half8 h2 = *reinterpret_cast<const half8*>(h + (size_t)s2 * NC + q8);
        const half8 h3 = *reinterpret_cast<const half8*>(h + (size_t)s3 * NC + q8);
        float w0 = hbits2f((unsigned short)(ra >> 17));
        float w1 = hbits2f((unsigned short)(rb >> 17));
        float w2 = hbits2f((unsigned short)(rc >> 17));
        float w3 = hbits2f((unsigned short)(rd >> 17));
#pragma unroll
        for (int j = 0; j < 8; ++j) {
            acc[j] += (float)h0[j] * w0 + (float)h1[j] * w1
                    + (float)h2[j] * w2 + (float)h3[j] * w3;
        }
    }
    for (; i < hi; ++i) {
        unsigned r0 = __builtin_nontemporal_load(recs + i);
        int s0 = r0 & 0x1FFFF;
        float w0 = hbits2f((unsigned short)(r0 >> 17));
        const half8 h0 = *reinterpret_cast<const half8*>(h + (size_t)s0 * NC + q8);
#pragma unroll
        for (int j = 0; j < 8; ++j) acc[j] += (float)h0[j] * w0;
    }
    // merge the 4 edge-quarters (lanes differ in bits 1-2 of sub)
#pragma unroll
    for (int j = 0; j < 8; ++j) {
        acc[j] += __shfl_xor(acc[j], 2);
        acc[j] += __shfl_xor(acc[j], 4);
    }
    float deg = degree[g];
    float d2 = deg * deg;
    const half8 hsv = *reinterpret_cast<const half8*>(h + (size_t)g * NC + q8);
    float v[8];
    float s8 = 0.f;
#pragma unroll
    for (int j = 0; j < 8; ++j) {
        v[j] = ALPHA_C * (float)hsv[j] + (1.f - ALPHA_C) * d2 * acc[j];
        s8 += v[j];
    }
    s8 += __shfl_xor(s8, 1);   // add the other class-half
    float inv = 1.f / s8;
#pragma unroll
    for (int j = 0; j < 8; ++j) v[j] *= inv;
    if (quarter == 0) {
        if (LAST) {
            float4 o0 = make_float4(v[0], v[1], v[2], v[3]);
            float4 o1 = make_float4(v[4], v[5], v[6], v[7]);
            *reinterpret_cast<float4*>(hout32 + (size_t)g * NC + q8) = o0;
            *reinterpret_cast<float4*>(hout32 + (size_t)g * NC + q8 + 4) = o1;
        } else {
            half8 o;
#pragma unroll
            for (int j = 0; j < 8; ++j) o[j] = (_Float16)v[j];
            *reinterpret_cast<half8*>(hout16 + (size_t)g * NC + q8) = o;
        }
    }
}

// ============ fallback (atomic-cursor CSR, fp32 gather) ============

__global__ void hist_kernel(const int* __restrict__ dst, int* __restrict__ counts) {
    int e = blockIdx.x * blockDim.x + threadIdx.x;
    if (e < NE) atomicAdd(&counts[dst[e]], 1);
}

__global__ void scatter_sort(const int* __restrict__ src, const int* __restrict__ dst,
                             const float* __restrict__ ew, const float* __restrict__ W,
                             const int* __restrict__ offsets, int* __restrict__ cursor,
                             int2* __restrict__ sorted) {
    int e = blockIdx.x * blockDim.x + threadIdx.x;
    if (e >= NE) return;
    int d = dst[e];
    int s = src[e];
    int pos = offsets[d] + atomicAdd(&cursor[d], 1);
    float w = ew[e] * W[s];
    sorted[pos] = make_int2(s, __float_as_int(w));
}

__global__ void gather1(const float* __restrict__ h, const int2* __restrict__ recs,
                        const int* __restrict__ offsets, const float* __restrict__ degree,
                        float* __restrict__ hout) {
    int t = blockIdx.x * blockDim.x + threadIdx.x;
    int g = t >> 2;
    int q = t & 3;
    if (g >= NN) return;
    int q4 = q * 4;
    int beg = offsets[g];
    int end = offsets[g + 1];
    float4 acc = make_float4(0.f, 0.f, 0.f, 0.f);
    for (int i = beg; i < end; ++i) {
        int2 r0 = recs[i];
        float w0 = __int_as_float(r0.y);
        const float4 h0 = *reinterpret_cast<const float4*>(h + (size_t)(r0.x & 0x1FFFF) * NC + q4);
        acc.x += h0.x * w0; acc.y += h0.y * w0; acc.z += h0.z * w0; acc.w += h0.w * w0;
    }
    float deg = degree[g];
    float d2 = deg * deg;
    const float4 hs = *reinterpret_cast<const float4*>(h + (size_t)g * NC + q4);
    float4 v;
    v.x = ALPHA_C * hs.x + (1.f - ALPHA_C) * d2 * acc.x;
    v.y = ALPHA_C * hs.y + (1.f - ALPHA_C) * d2 * acc.y;
    v.z = ALPHA_C * hs.z + (1.f - ALPHA_C) * d2 * acc.z;
    v.w = ALPHA_C * hs.w + (1.f - ALPHA_C) * d2 * acc.w;
    float s4 = v.x + v.y + v.z + v.w;
    s4 += __shfl_xor(s4, 1);
    s4 += __shfl_xor(s4, 2);
    float inv = 1.f / s4;
    v.x *= inv; v.y *= inv; v.z *= inv; v.w *= inv;
    *reinterpret_cast<float4*>(hout + (size_t)g * NC + q4) = v;
}

// ============ launch ============

extern "C" void kernel_launch(void* const* d_in, const int* in_sizes, int n_in,
                              void* d_out, int out_size, void* d_ws, size_t ws_size,
                              hipStream_t stream)
{
    const float* x      = (const float*)d_in[0];
    const float* W      = (const float*)d_in[1];
    const float* ew     = (const float*)d_in[2];
    const float* degree = (const float*)d_in[3];
    const int*   eidx   = (const int*)d_in[4];
    const int* src = eidx;
    const int* dst = eidx + NE;
    float* out = (float*)d_out;

    const int node_blocks8 = (NN * 8 + 255) / 256;     // 8 lanes per node
    const int node_blocks4 = (NN * 4 + 255) / 256;
    const int edge_blocks  = (NE + 255) / 256;

    const size_t recs_elems   = (size_t)NE;            // int2 (build)
    const size_t recs4_elems  = (size_t)NE;            // u32 (gather)
    const size_t h16_elems    = (size_t)NN * NC;       // _Float16, x2 buffers
    const size_t counts_elems = (size_t)NBUK * NBLK + 1;
    const size_t off_elems    = (size_t)NN + 1;
    const size_t need = recs_elems * 8 + recs4_elems * 4 + h16_elems * 2 * 2
                      + counts_elems * 4 + off_elems * 4 + 1024 * 4 + 64;

    if (ws_size >= need) {
        int2*      recs      = (int2*)d_ws;
        unsigned*  recs4     = (unsigned*)(recs + recs_elems);
        _Float16*  h16a      = (_Float16*)(recs4 + recs4_elems);
        _Float16*  h16b      = h16a + h16_elems;
        int*       counts    = (int*)(h16b + h16_elems);
        int*       offsets   = counts + counts_elems;
        int*       blockSums = offsets + off_elems;

        bucket_count<<<NBLK, 1024, 0, stream>>>(dst, counts);
        const int n_scan = NBUK * NBLK;                 // 100096
        const int NB = (n_scan + 1023) / 1024;          // 98
        scanA<<<NB, 256, 0, stream>>>(counts, blockSums, n_scan);
        scanB<<<1, 1024, 0, stream>>>(blockSums, NB);
        scanC<<<(n_scan + 255) / 256, 256, 0, stream>>>(counts, blockSums, n_scan);
        bucket_scatter<<<NBLK, 1024, 0, stream>>>(src, dst, ew, W, counts, recs);
        bucket_sort<<<NBUK, 512, 0, stream>>>(recs, recs4, counts, offsets);

        f32_to_f16<<<(NN * NC / 4 + 255) / 256, 256, 0, stream>>>(x, h16a);
        gather_f16<false><<<node_blocks8, 256, 0, stream>>>(h16a, recs4, offsets, degree, h16b, nullptr);
        gather_f16<false><<<node_blocks8, 256, 0, stream>>>(h16b, recs4, offsets, degree, h16a, nullptr);
        gather_f16<false><<<node_blocks8, 256, 0, stream>>>(h16a, recs4, offsets, degree, h16b, nullptr);
        gather_f16<true ><<<node_blocks8, 256, 0, stream>>>(h16b, recs4, offsets, degree, nullptr, out);
        return;
    }

    // -------- fallback: single CSR with cursor atomics, fp32 gather --------
    {
        const size_t bufA_elems = (size_t)NN * NC;
        int2*  sorted    = (int2*)d_ws;
        float* bufA      = (float*)(sorted + NE);
        int*   offsets   = (int*)(bufA + bufA_elems);
        int*   cursor    = offsets + (NN + 1);
        int*   blockSums = cursor + NN;

        (void)hipMemsetAsync(offsets, 0, (size_t)(2 * NN + 1) * sizeof(int), stream);
        hist_kernel<<<edge_blocks, 256, 0, stream>>>(dst, offsets);
        const int NB = (NN + 1023) / 1024;
        scanA<<<NB, 256, 0, stream>>>(offsets, blockSums, NN);
        scanB<<<1, 1024, 0, stream>>>(blockSums, NB);
        scanC<<<(NN + 255) / 256, 256, 0, stream>>>(offsets, blockSums, NN);
        scatter_sort<<<edge_blocks, 256, 0, stream>>>(src, dst, ew, W, offsets, cursor, sorted);

        const float* hin = x;
        float* houts[NLAYERS] = {bufA, out, bufA, out};
        for (int l = 0; l < NLAYERS; ++l) {
            gather1<<<node_blocks4, 256, 0, stream>>>(hin, sorted, offsets, degree, houts[l]);
            hin = houts[l];
        }
    }
}

// Round 16
// 156.933 us; speedup vs baseline: 2.0402x; 1.4607x over previous
//
#include <hip/hip_runtime.h>

#define NN 100000
#define NC 16
#define NE 3200000
#define NLAYERS 4
#define ALPHA_C 0.5f

#define BSHIFT 8
#define NBUK 391            // ceil(NN / 256)
#define EPB 12544           // edges per block -> exactly 256 blocks
#define NBLK 256
#define CAP 9728            // LDS staging capacity per bucket (mean 8192, +17 sigma)
#define LCAP 6144           // gather LDS rec window (mean 1024, +160 sigma)

typedef __attribute__((ext_vector_type(4))) _Float16 half4;
typedef __attribute__((ext_vector_type(8))) _Float16 half8;

static __device__ __forceinline__ unsigned short f2h_bits(float w) {
    _Float16 h = (_Float16)w;
    unsigned short b;
    __builtin_memcpy(&b, &h, 2);
    return b;
}
static __device__ __forceinline__ float hbits2f(unsigned short b) {
    _Float16 h;
    __builtin_memcpy(&h, &b, 2);
    return (float)h;
}

// ============ build phase (LDS atomics only) ============

__global__ __launch_bounds__(1024) void bucket_count(const int* __restrict__ dst,
                                                     int* __restrict__ counts) {
    __shared__ int h[NBUK];
    for (int i = threadIdx.x; i < NBUK; i += 1024) h[i] = 0;
    __syncthreads();
    int base = blockIdx.x * EPB;
    int nedge = min(EPB, NE - base);
    for (int i = threadIdx.x; i < nedge; i += 1024)
        atomicAdd(&h[dst[base + i] >> BSHIFT], 1);
    __syncthreads();
    for (int i = threadIdx.x; i < NBUK; i += 1024)
        counts[i * NBLK + blockIdx.x] = h[i];   // bucket-major for the scan
}

// Exclusive scan, 1024 elements per block (256 threads x 4 elems).
__global__ void scanA(int* __restrict__ data, int* __restrict__ blockSums, int n) {
    __shared__ int lds[256];
    int base = blockIdx.x * 1024 + threadIdx.x * 4;
    int v[4] = {0, 0, 0, 0};
#pragma unroll
    for (int i = 0; i < 4; ++i) { int idx = base + i; if (idx < n) v[i] = data[idx]; }
    int tsum = v[0] + v[1] + v[2] + v[3];
    lds[threadIdx.x] = tsum;
    __syncthreads();
    for (int off = 1; off < 256; off <<= 1) {
        int t = (threadIdx.x >= off) ? lds[threadIdx.x - off] : 0;
        __syncthreads();
        lds[threadIdx.x] += t;
        __syncthreads();
    }
    if (threadIdx.x == 255) blockSums[blockIdx.x] = lds[255];
    int run = lds[threadIdx.x] - tsum;
#pragma unroll
    for (int i = 0; i < 4; ++i) {
        int idx = base + i;
        if (idx < n) { int old = v[i]; data[idx] = run; run += old; }
    }
}

__global__ void scanB(int* __restrict__ blockSums, int nb) {
    __shared__ int lds[1024];
    int t = threadIdx.x;
    lds[t] = (t < nb) ? blockSums[t] : 0;
    __syncthreads();
    for (int off = 1; off < 1024; off <<= 1) {
        int v = (t >= off) ? lds[t - off] : 0;
        __syncthreads();
        lds[t] += v;
        __syncthreads();
    }
    if (t < nb) blockSums[t] = (t == 0) ? 0 : lds[t - 1];
}

__global__ void scanC(int* __restrict__ data, const int* __restrict__ blockSums, int n) {
    int idx = blockIdx.x * blockDim.x + threadIdx.x;
    if (idx < n) data[idx] += blockSums[idx >> 10];
    if (idx == 0) data[n] = NE;
}

// LDS-staged scatter: histogram -> LDS scan -> LDS placement (bucket-ordered)
// -> linear coalesced write-out. rec.x = src | (local_dst<<17), rec.y = w bits.
__global__ __launch_bounds__(1024) void bucket_scatter(
        const int* __restrict__ src, const int* __restrict__ dst,
        const float* __restrict__ ew, const float* __restrict__ W,
        const int* __restrict__ scanned, int2* __restrict__ recs) {
    __shared__ int2 lrec[EPB];               // 100352 B
    __shared__ unsigned short lbid[EPB];     // 25088 B
    __shared__ int h[NBUK];
    __shared__ int lbase[NBUK];
    __shared__ int delta[NBUK];
    __shared__ int sc[512];
    int t = threadIdx.x;
    int blk = blockIdx.x;
    for (int i = t; i < NBUK; i += 1024) h[i] = 0;
    __syncthreads();
    int base = blk * EPB;
    int nedge = min(EPB, NE - base);
    for (int i = t; i < nedge; i += 1024)
        atomicAdd(&h[dst[base + i] >> BSHIFT], 1);
    __syncthreads();
    // exclusive LDS scan of h -> lbase; delta = global base - local base
    if (t < 512) sc[t] = (t < NBUK) ? h[t] : 0;
    __syncthreads();
    for (int off = 1; off < 512; off <<= 1) {
        int v = (t >= off && t < 512) ? sc[t - off] : 0;
        __syncthreads();
        if (t < 512) sc[t] += v;
        __syncthreads();
    }
    if (t < NBUK) {
        int excl = sc[t] - h[t];
        lbase[t] = excl;
        delta[t] = scanned[t * NBLK + blk] - excl;
        h[t] = 0;
    }
    __syncthreads();
    // placement into LDS, bucket-ordered
    for (int i = t; i < nedge; i += 1024) {
        int e = base + i;
        int d = dst[e];
        int s = src[e];
        float w = ew[e] * W[s];
        int b = d >> BSHIFT;
        int r = atomicAdd(&h[b], 1);
        int slot = lbase[b] + r;
        lrec[slot] = make_int2(s | ((d & 255) << 17), __float_as_int(w));
        lbid[slot] = (unsigned short)b;
    }
    __syncthreads();
    // coalesced write-out: consecutive threads -> consecutive addresses per run
    for (int i = t; i < nedge; i += 1024) {
        int b = lbid[i];
        recs[i + delta[b]] = lrec[i];
    }
}

// One block (512 thr) per bucket: stage 8B records in LDS, counting-sort the
// 256 local dsts, write CSR offsets, and emit PACKED 4B records
// (src 17b | fp16-w-no-sign 15b), fully dst-sorted.
__global__ void bucket_sort(const int2* __restrict__ recs, unsigned* __restrict__ recs4,
                            const int* __restrict__ scanned, int* __restrict__ offsets) {
    __shared__ int2 lrec[CAP];
    __shared__ int hcnt[256];
    __shared__ int hscan[256];
    __shared__ int hexcl[256];
    int b = blockIdx.x;
    int t = threadIdx.x;
    int beg = scanned[b * NBLK];
    int end = (b == NBUK - 1) ? NE : scanned[(b + 1) * NBLK];
    int cnt = end - beg;
    if (t < 256) hcnt[t] = 0;
    __syncthreads();
    for (int i = t; i < cnt && i < CAP; i += 512) {
        int2 rv = recs[beg + i];
        lrec[i] = rv;
        atomicAdd(&hcnt[(rv.x >> 17) & 255], 1);
    }
    __syncthreads();
    if (t < 256) hscan[t] = hcnt[t];
    __syncthreads();
    for (int off = 1; off < 256; off <<= 1) {
        int v = 0;
        if (t >= off && t < 256) v = hscan[t - off];
        __syncthreads();
        if (t < 256) hscan[t] += v;
        __syncthreads();
    }
    if (t < 256) {
        hexcl[t] = hscan[t] - hcnt[t];
        int d = (b << BSHIFT) + t;
        if (d < NN) offsets[d] = beg + hexcl[t];
        hcnt[t] = 0;
    }
    if (b == NBUK - 1 && t == 0) offsets[NN] = NE;
    __syncthreads();
    for (int i = t; i < cnt && i < CAP; i += 512) {
        int2 rv = lrec[i];
        int ld = (rv.x >> 17) & 255;
        int r = atomicAdd(&hcnt[ld], 1);
        unsigned short hb = f2h_bits(__int_as_float(rv.y));
        recs4[beg + hexcl[ld] + r] = (unsigned)(rv.x & 0x1FFFF) | ((unsigned)hb << 17);
    }
}

// ============ fp32 -> fp16 conversion (once) ============
__global__ void f32_to_f16(const float* __restrict__ in, _Float16* __restrict__ out) {
    int i = blockIdx.x * blockDim.x + threadIdx.x;
    int base = i * 4;
    if (base < NN * NC) {
        float4 v = *reinterpret_cast<const float4*>(in + base);
        half4 o;
        o.x = (_Float16)v.x; o.y = (_Float16)v.y;
        o.z = (_Float16)v.z; o.w = (_Float16)v.w;
        *reinterpret_cast<half4*>(out + base) = o;
    }
}

// ============ per-layer gather (fp16 h, packed 4B recs staged in LDS, 8 lanes/node) ============
// Block = 256 thr = 32 nodes (NN % 32 == 0 -> no tail). The block's nodes own a
// contiguous ~1K-rec CSR window: stage it into LDS with coalesced loads, then
// per-lane loops read recs from LDS (off the VMEM port; dup reads broadcast).
// sub = t&7: q = sub&1 owns classes [8q,8q+8); quarter = sub>>1 owns an edge
// quarter. Quarters merged via shfl_xor(2,4); rownorm via shfl_xor(1).
template<bool LAST>
__global__ __launch_bounds__(256) void gather_f16(
        const _Float16* __restrict__ h, const unsigned* __restrict__ recs,
        const int* __restrict__ offsets, const float* __restrict__ degree,
        _Float16* __restrict__ hout16, float* __restrict__ hout32) {
    __shared__ unsigned lrec[LCAP];
    __shared__ int srange[2];
    int tid = threadIdx.x;
    int gfirst = blockIdx.x * 32;
    if (tid < 2) srange[tid] = offsets[gfirst + tid * 32];
    __syncthreads();
    int beg0 = srange[0];
    int n0 = srange[1] - beg0;
    bool staged = (n0 <= LCAP);
    if (staged) {
        for (int i = tid; i < n0; i += 256)
            lrec[i] = recs[beg0 + i];    // coalesced
    }
    __syncthreads();
    int g = gfirst + (tid >> 3);
    int sub = tid & 7;
    int q8 = (sub & 1) * 8;
    int quarter = sub >> 1;
    int beg = offsets[g];
    int end = offsets[g + 1];
    int len = end - beg;
    int qlen = (len + 3) >> 2;
    int lo = beg + quarter * qlen;
    int hi = lo + qlen;
    if (lo > end) lo = end;
    if (hi > end) hi = end;
    float acc[8] = {0.f, 0.f, 0.f, 0.f, 0.f, 0.f, 0.f, 0.f};
    if (staged) {
        int i = lo - beg0;
        int hh = hi - beg0;
        for (; i + 4 <= hh; i += 4) {
            unsigned r0 = lrec[i];
            unsigned r1 = lrec[i + 1];
            unsigned r2 = lrec[i + 2];
            unsigned r3 = lrec[i + 3];
            int s0 = r0 & 0x1FFFF, s1 = r1 & 0x1FFFF, s2 = r2 & 0x1FFFF, s3 = r3 & 0x1FFFF;
            const half8 h0 = *reinterpret_cast<const half8*>(h + (size_t)s0 * NC + q8);
            const half8 h1 = *reinterpret_cast<const half8*>(h + (size_t)s1 * NC + q8);
            const half8 h2 = *reinterpret_cast<const half8*>(h + (size_t)s2 * NC + q8);
            const half8 h3 = *reinterpret_cast<const half8*>(h + (size_t)s3 * NC + q8);
            float w0 = hbits2f((unsigned short)(r0 >> 17));
            float w1 = hbits2f((unsigned short)(r1 >> 17));
            float w2 = hbits2f((unsigned short)(r2 >> 17));
            float w3 = hbits2f((unsigned short)(r3 >> 17));
#pragma unroll
            for (int j = 0; j < 8; ++j) {
                acc[j] += (float)h0[j] * w0 + (float)h1[j] * w1
                        + (float)h2[j] * w2 + (float)h3[j] * w3;
            }
        }
        for (; i < hh; ++i) {
            unsigned r0 = lrec[i];
            int s0 = r0 & 0x1FFFF;
            float w0 = hbits2f((unsigned short)(r0 >> 17));
            const half8 h0 = *reinterpret_cast<const half8*>(h + (size_t)s0 * NC + q8);
#pragma unroll
            for (int j = 0; j < 8; ++j) acc[j] += (float)h0[j] * w0;
        }
    } else {
        int i = lo;
        for (; i + 4 <= hi; i += 4) {
            unsigned r0 = __builtin_nontemporal_load(recs + i);
            unsigned r1 = __builtin_nontemporal_load(recs + i + 1);
            unsigned r2 = __builtin_nontemporal_load(recs + i + 2);
            unsigned r3 = __builtin_nontemporal_load(recs + i + 3);
            int s0 = r0 & 0x1FFFF, s1 = r1 & 0x1FFFF, s2 = r2 & 0x1FFFF, s3 = r3 & 0x1FFFF;
            const half8 h0 = *reinterpret_cast<const half8*>(h + (size_t)s0 * NC + q8);
            const half8 h1 = *reinterpret_cast<const half8*>(h + (size_t)s1 * NC + q8);
            const half8 h2 = *reinterpret_cast<const half8*>(h + (size_t)s2 * NC + q8);
            const half8 h3 = *reinterpret_cast<const half8*>(h + (size_t)s3 * NC + q8);
            float w0 = hbits2f((unsigned short)(r0 >> 17));
            float w1 = hbits2f((unsigned short)(r1 >> 17));
            float w2 = hbits2f((unsigned short)(r2 >> 17));
            float w3 = hbits2f((unsigned short)(r3 >> 17));
#pragma unroll
            for (int j = 0; j < 8; ++j) {
                acc[j] += (float)h0[j] * w0 + (float)h1[j] * w1
                        + (float)h2[j] * w2 + (float)h3[j] * w3;
            }
        }
        for (; i < hi; ++i) {
            unsigned r0 = __builtin_nontemporal_load(recs + i);
            int s0 = r0 & 0x1FFFF;
            float w0 = hbits2f((unsigned short)(r0 >> 17));
            const half8 h0 = *reinterpret_cast<const half8*>(h + (size_t)s0 * NC + q8);
#pragma unroll
            for (int j = 0; j < 8; ++j) acc[j] += (float)h0[j] * w0;
        }
    }
    // merge the 4 edge-quarters (lanes differ in bits 1-2 of sub)
#pragma unroll
    for (int j = 0; j < 8; ++j) {
        acc[j] += __shfl_xor(acc[j], 2);
        acc[j] += __shfl_xor(acc[j], 4);
    }
    float deg = degree[g];
    float d2 = deg * deg;
    const half8 hsv = *reinterpret_cast<const half8*>(h + (size_t)g * NC + q8);
    float v[8];
    float s8 = 0.f;
#pragma unroll
    for (int j = 0; j < 8; ++j) {
        v[j] = ALPHA_C * (float)hsv[j] + (1.f - ALPHA_C) * d2 * acc[j];
        s8 += v[j];
    }
    s8 += __shfl_xor(s8, 1);   // add the other class-half
    float inv = 1.f / s8;
#pragma unroll
    for (int j = 0; j < 8; ++j) v[j] *= inv;
    if (quarter == 0) {
        if (LAST) {
            float4 o0 = make_float4(v[0], v[1], v[2], v[3]);
            float4 o1 = make_float4(v[4], v[5], v[6], v[7]);
            *reinterpret_cast<float4*>(hout32 + (size_t)g * NC + q8) = o0;
            *reinterpret_cast<float4*>(hout32 + (size_t)g * NC + q8 + 4) = o1;
        } else {
            half8 o;
#pragma unroll
            for (int j = 0; j < 8; ++j) o[j] = (_Float16)v[j];
            *reinterpret_cast<half8*>(hout16 + (size_t)g * NC + q8) = o;
        }
    }
}

// ============ fallback (atomic-cursor CSR, fp32 gather) ============

__global__ void hist_kernel(const int* __restrict__ dst, int* __restrict__ counts) {
    int e = blockIdx.x * blockDim.x + threadIdx.x;
    if (e < NE) atomicAdd(&counts[dst[e]], 1);
}

__global__ void scatter_sort(const int* __restrict__ src, const int* __restrict__ dst,
                             const float* __restrict__ ew, const float* __restrict__ W,
                             const int* __restrict__ offsets, int* __restrict__ cursor,
                             int2* __restrict__ sorted) {
    int e = blockIdx.x * blockDim.x + threadIdx.x;
    if (e >= NE) return;
    int d = dst[e];
    int s = src[e];
    int pos = offsets[d] + atomicAdd(&cursor[d], 1);
    float w = ew[e] * W[s];
    sorted[pos] = make_int2(s, __float_as_int(w));
}

__global__ void gather1(const float* __restrict__ h, const int2* __restrict__ recs,
                        const int* __restrict__ offsets, const float* __restrict__ degree,
                        float* __restrict__ hout) {
    int t = blockIdx.x * blockDim.x + threadIdx.x;
    int g = t >> 2;
    int q = t & 3;
    if (g >= NN) return;
    int q4 = q * 4;
    int beg = offsets[g];
    int end = offsets[g + 1];
    float4 acc = make_float4(0.f, 0.f, 0.f, 0.f);
    for (int i = beg; i < end; ++i) {
        int2 r0 = recs[i];
        float w0 = __int_as_float(r0.y);
        const float4 h0 = *reinterpret_cast<const float4*>(h + (size_t)(r0.x & 0x1FFFF) * NC + q4);
        acc.x += h0.x * w0; acc.y += h0.y * w0; acc.z += h0.z * w0; acc.w += h0.w * w0;
    }
    float deg = degree[g];
    float d2 = deg * deg;
    const float4 hs = *reinterpret_cast<const float4*>(h + (size_t)g * NC + q4);
    float4 v;
    v.x = ALPHA_C * hs.x + (1.f - ALPHA_C) * d2 * acc.x;
    v.y = ALPHA_C * hs.y + (1.f - ALPHA_C) * d2 * acc.y;
    v.z = ALPHA_C * hs.z + (1.f - ALPHA_C) * d2 * acc.z;
    v.w = ALPHA_C * hs.w + (1.f - ALPHA_C) * d2 * acc.w;
    float s4 = v.x + v.y + v.z + v.w;
    s4 += __shfl_xor(s4, 1);
    s4 += __shfl_xor(s4, 2);
    float inv = 1.f / s4;
    v.x *= inv; v.y *= inv; v.z *= inv; v.w *= inv;
    *reinterpret_cast<float4*>(hout + (size_t)g * NC + q4) = v;
}

// ============ launch ============

extern "C" void kernel_launch(void* const* d_in, const int* in_sizes, int n_in,
                              void* d_out, int out_size, void* d_ws, size_t ws_size,
                              hipStream_t stream)
{
    const float* x      = (const float*)d_in[0];
    const float* W      = (const float*)d_in[1];
    const float* ew     = (const float*)d_in[2];
    const float* degree = (const float*)d_in[3];
    const int*   eidx   = (const int*)d_in[4];
    const int* src = eidx;
    const int* dst = eidx + NE;
    float* out = (float*)d_out;

    const int gather_blocks = NN / 32;                 // 3125, exact
    const int node_blocks4  = (NN * 4 + 255) / 256;
    const int edge_blocks   = (NE + 255) / 256;

    const size_t recs_elems   = (size_t)NE;            // int2 (build)
    const size_t recs4_elems  = (size_t)NE;            // u32 (gather)
    const size_t h16_elems    = (size_t)NN * NC;       // _Float16, x2 buffers
    const size_t counts_elems = (size_t)NBUK * NBLK + 1;
    const size_t off_elems    = (size_t)NN + 1;
    const size_t need = recs_elems * 8 + recs4_elems * 4 + h16_elems * 2 * 2
                      + counts_elems * 4 + off_elems * 4 + 1024 * 4 + 64;

    if (ws_size >= need) {
        int2*      recs      = (int2*)d_ws;
        unsigned*  recs4     = (unsigned*)(recs + recs_elems);
        _Float16*  h16a      = (_Float16*)(recs4 + recs4_elems);
        _Float16*  h16b      = h16a + h16_elems;
        int*       counts    = (int*)(h16b + h16_elems);
        int*       offsets   = counts + counts_elems;
        int*       blockSums = offsets + off_elems;

        bucket_count<<<NBLK, 1024, 0, stream>>>(dst, counts);
        const int n_scan = NBUK * NBLK;                 // 100096
        const int NB = (n_scan + 1023) / 1024;          // 98
        scanA<<<NB, 256, 0, stream>>>(counts, blockSums, n_scan);
        scanB<<<1, 1024, 0, stream>>>(blockSums, NB);
        scanC<<<(n_scan + 255) / 256, 256, 0, stream>>>(counts, blockSums, n_scan);
        bucket_scatter<<<NBLK, 1024, 0, stream>>>(src, dst, ew, W, counts, recs);
        bucket_sort<<<NBUK, 512, 0, stream>>>(recs, recs4, counts, offsets);

        f32_to_f16<<<(NN * NC / 4 + 255) / 256, 256, 0, stream>>>(x, h16a);
        gather_f16<false><<<gather_blocks, 256, 0, stream>>>(h16a, recs4, offsets, degree, h16b, nullptr);
        gather_f16<false><<<gather_blocks, 256, 0, stream>>>(h16b, recs4, offsets, degree, h16a, nullptr);
        gather_f16<false><<<gather_blocks, 256, 0, stream>>>(h16a, recs4, offsets, degree, h16b, nullptr);
        gather_f16<true ><<<gather_blocks, 256, 0, stream>>>(h16b, recs4, offsets, degree, nullptr, out);
        return;
    }

    // -------- fallback: single CSR with cursor atomics, fp32 gather --------
    {
        const size_t bufA_elems = (size_t)NN * NC;
        int2*  sorted    = (int2*)d_ws;
        float* bufA      = (float*)(sorted + NE);
        int*   offsets   = (int*)(bufA + bufA_elems);
        int*   cursor    = offsets + (NN + 1);
        int*   blockSums = cursor + NN;

        (void)hipMemsetAsync(offsets, 0, (size_t)(2 * NN + 1) * sizeof(int), stream);
        hist_kernel<<<edge_blocks, 256, 0, stream>>>(dst, offsets);
        const int NB = (NN + 1023) / 1024;
        scanA<<<NB, 256, 0, stream>>>(offsets, blockSums, NN);
        scanB<<<1, 1024, 0, stream>>>(blockSums, NB);
        scanC<<<(NN + 255) / 256, 256, 0, stream>>>(offsets, blockSums, NN);
        scatter_sort<<<edge_blocks, 256, 0, stream>>>(src, dst, ew, W, offsets, cursor, sorted);

        const float* hin = x;
        float* houts[NLAYERS] = {bufA, out, bufA, out};
        for (int l = 0; l < NLAYERS; ++l) {
            gather1<<<node_blocks4, 256, 0, stream>>>(hin, sorted, offsets, degree, houts[l]);
            hin = houts[l];
        }
    }
}

// Round 17
// 151.492 us; speedup vs baseline: 2.1134x; 1.0359x over previous
//
#include <hip/hip_runtime.h>

#define NN 100000
#define NC 16
#define NE 3200000
#define NLAYERS 4
#define ALPHA_C 0.5f

#define BSHIFT 8
#define NBUK 391            // ceil(NN / 256)
#define EPB 12544           // edges per block -> exactly 256 blocks
#define NBLK 256
#define CAP 9728            // LDS staging capacity per bucket (mean 8192, +17 sigma)
#define LCAP 4096           // gather LDS rec window (mean 1024, +96 sigma) -> 16.4KB, 8 blocks/CU

typedef __attribute__((ext_vector_type(4))) _Float16 half4;
typedef __attribute__((ext_vector_type(8))) _Float16 half8;

static __device__ __forceinline__ unsigned short f2h_bits(float w) {
    _Float16 h = (_Float16)w;
    unsigned short b;
    __builtin_memcpy(&b, &h, 2);
    return b;
}
static __device__ __forceinline__ float hbits2f(unsigned short b) {
    _Float16 h;
    __builtin_memcpy(&h, &b, 2);
    return (float)h;
}

// ============ build phase (LDS atomics only) ============

__global__ __launch_bounds__(1024) void bucket_count(const int* __restrict__ dst,
                                                     int* __restrict__ counts) {
    __shared__ int h[NBUK];
    for (int i = threadIdx.x; i < NBUK; i += 1024) h[i] = 0;
    __syncthreads();
    int base = blockIdx.x * EPB;
    int nedge = min(EPB, NE - base);
    for (int i = threadIdx.x; i < nedge; i += 1024)
        atomicAdd(&h[dst[base + i] >> BSHIFT], 1);
    __syncthreads();
    for (int i = threadIdx.x; i < NBUK; i += 1024)
        counts[i * NBLK + blockIdx.x] = h[i];   // bucket-major for the scan
}

// Exclusive scan, 1024 elements per block (256 threads x 4 elems).
__global__ void scanA(int* __restrict__ data, int* __restrict__ blockSums, int n) {
    __shared__ int lds[256];
    int base = blockIdx.x * 1024 + threadIdx.x * 4;
    int v[4] = {0, 0, 0, 0};
#pragma unroll
    for (int i = 0; i < 4; ++i) { int idx = base + i; if (idx < n) v[i] = data[idx]; }
    int tsum = v[0] + v[1] + v[2] + v[3];
    lds[threadIdx.x] = tsum;
    __syncthreads();
    for (int off = 1; off < 256; off <<= 1) {
        int t = (threadIdx.x >= off) ? lds[threadIdx.x - off] : 0;
        __syncthreads();
        lds[threadIdx.x] += t;
        __syncthreads();
    }
    if (threadIdx.x == 255) blockSums[blockIdx.x] = lds[255];
    int run = lds[threadIdx.x] - tsum;
#pragma unroll
    for (int i = 0; i < 4; ++i) {
        int idx = base + i;
        if (idx < n) { int old = v[i]; data[idx] = run; run += old; }
    }
}

__global__ void scanB(int* __restrict__ blockSums, int nb) {
    __shared__ int lds[1024];
    int t = threadIdx.x;
    lds[t] = (t < nb) ? blockSums[t] : 0;
    __syncthreads();
    for (int off = 1; off < 1024; off <<= 1) {
        int v = (t >= off) ? lds[t - off] : 0;
        __syncthreads();
        lds[t] += v;
        __syncthreads();
    }
    if (t < nb) blockSums[t] = (t == 0) ? 0 : lds[t - 1];
}

__global__ void scanC(int* __restrict__ data, const int* __restrict__ blockSums, int n) {
    int idx = blockIdx.x * blockDim.x + threadIdx.x;
    if (idx < n) data[idx] += blockSums[idx >> 10];
    if (idx == 0) data[n] = NE;
}

// LDS-staged scatter: histogram -> LDS scan -> LDS placement (bucket-ordered)
// -> linear coalesced write-out. rec.x = src | (local_dst<<17), rec.y = w bits.
__global__ __launch_bounds__(1024) void bucket_scatter(
        const int* __restrict__ src, const int* __restrict__ dst,
        const float* __restrict__ ew, const float* __restrict__ W,
        const int* __restrict__ scanned, int2* __restrict__ recs) {
    __shared__ int2 lrec[EPB];               // 100352 B
    __shared__ unsigned short lbid[EPB];     // 25088 B
    __shared__ int h[NBUK];
    __shared__ int lbase[NBUK];
    __shared__ int delta[NBUK];
    __shared__ int sc[512];
    int t = threadIdx.x;
    int blk = blockIdx.x;
    for (int i = t; i < NBUK; i += 1024) h[i] = 0;
    __syncthreads();
    int base = blk * EPB;
    int nedge = min(EPB, NE - base);
    for (int i = t; i < nedge; i += 1024)
        atomicAdd(&h[dst[base + i] >> BSHIFT], 1);
    __syncthreads();
    // exclusive LDS scan of h -> lbase; delta = global base - local base
    if (t < 512) sc[t] = (t < NBUK) ? h[t] : 0;
    __syncthreads();
    for (int off = 1; off < 512; off <<= 1) {
        int v = (t >= off && t < 512) ? sc[t - off] : 0;
        __syncthreads();
        if (t < 512) sc[t] += v;
        __syncthreads();
    }
    if (t < NBUK) {
        int excl = sc[t] - h[t];
        lbase[t] = excl;
        delta[t] = scanned[t * NBLK + blk] - excl;
        h[t] = 0;
    }
    __syncthreads();
    // placement into LDS, bucket-ordered
    for (int i = t; i < nedge; i += 1024) {
        int e = base + i;
        int d = dst[e];
        int s = src[e];
        float w = ew[e] * W[s];
        int b = d >> BSHIFT;
        int r = atomicAdd(&h[b], 1);
        int slot = lbase[b] + r;
        lrec[slot] = make_int2(s | ((d & 255) << 17), __float_as_int(w));
        lbid[slot] = (unsigned short)b;
    }
    __syncthreads();
    // coalesced write-out: consecutive threads -> consecutive addresses per run
    for (int i = t; i < nedge; i += 1024) {
        int b = lbid[i];
        recs[i + delta[b]] = lrec[i];
    }
}

// One block (512 thr) per bucket: stage 8B records in LDS, counting-sort the
// 256 local dsts, write CSR offsets, and emit PACKED 4B records
// (src 17b | fp16-w-no-sign 15b), fully dst-sorted.
__global__ void bucket_sort(const int2* __restrict__ recs, unsigned* __restrict__ recs4,
                            const int* __restrict__ scanned, int* __restrict__ offsets) {
    __shared__ int2 lrec[CAP];
    __shared__ int hcnt[256];
    __shared__ int hscan[256];
    __shared__ int hexcl[256];
    int b = blockIdx.x;
    int t = threadIdx.x;
    int beg = scanned[b * NBLK];
    int end = (b == NBUK - 1) ? NE : scanned[(b + 1) * NBLK];
    int cnt = end - beg;
    if (t < 256) hcnt[t] = 0;
    __syncthreads();
    for (int i = t; i < cnt && i < CAP; i += 512) {
        int2 rv = recs[beg + i];
        lrec[i] = rv;
        atomicAdd(&hcnt[(rv.x >> 17) & 255], 1);
    }
    __syncthreads();
    if (t < 256) hscan[t] = hcnt[t];
    __syncthreads();
    for (int off = 1; off < 256; off <<= 1) {
        int v = 0;
        if (t >= off && t < 256) v = hscan[t - off];
        __syncthreads();
        if (t < 256) hscan[t] += v;
        __syncthreads();
    }
    if (t < 256) {
        hexcl[t] = hscan[t] - hcnt[t];
        int d = (b << BSHIFT) + t;
        if (d < NN) offsets[d] = beg + hexcl[t];
        hcnt[t] = 0;
    }
    if (b == NBUK - 1 && t == 0) offsets[NN] = NE;
    __syncthreads();
    for (int i = t; i < cnt && i < CAP; i += 512) {
        int2 rv = lrec[i];
        int ld = (rv.x >> 17) & 255;
        int r = atomicAdd(&hcnt[ld], 1);
        unsigned short hb = f2h_bits(__int_as_float(rv.y));
        recs4[beg + hexcl[ld] + r] = (unsigned)(rv.x & 0x1FFFF) | ((unsigned)hb << 17);
    }
}

// ============ fp32 -> fp16 conversion (once) ============
__global__ void f32_to_f16(const float* __restrict__ in, _Float16* __restrict__ out) {
    int i = blockIdx.x * blockDim.x + threadIdx.x;
    int base = i * 4;
    if (base < NN * NC) {
        float4 v = *reinterpret_cast<const float4*>(in + base);
        half4 o;
        o.x = (_Float16)v.x; o.y = (_Float16)v.y;
        o.z = (_Float16)v.z; o.w = (_Float16)v.w;
        *reinterpret_cast<half4*>(out + base) = o;
    }
}

// ============ per-layer gather (fp16 h, packed 4B recs staged in LDS, 8 lanes/node) ============
// Block = 256 thr = 32 nodes. The block's contiguous ~1K-rec CSR window is
// staged into 16KB LDS (coalesced); per-lane loops read recs from LDS.
// 16.4KB LDS + launch_bounds(256,8) -> 8 blocks/CU = 32 waves (max occupancy).
// sub = t&7: q = sub&1 owns classes [8q,8q+8); quarter = sub>>1 owns an edge
// quarter. Quarters merged via shfl_xor(2,4); rownorm via shfl_xor(1).
template<bool LAST>
__global__ __launch_bounds__(256, 8) void gather_f16(
        const _Float16* __restrict__ h, const unsigned* __restrict__ recs,
        const int* __restrict__ offsets, const float* __restrict__ degree,
        _Float16* __restrict__ hout16, float* __restrict__ hout32) {
    __shared__ unsigned lrec[LCAP];
    __shared__ int srange[2];
    int tid = threadIdx.x;
    int gfirst = blockIdx.x * 32;
    if (tid < 2) srange[tid] = offsets[gfirst + tid * 32];
    __syncthreads();
    int beg0 = srange[0];
    int n0 = srange[1] - beg0;
    bool staged = (n0 <= LCAP);
    if (staged) {
        for (int i = tid; i < n0; i += 256)
            lrec[i] = recs[beg0 + i];    // coalesced
    }
    __syncthreads();
    int g = gfirst + (tid >> 3);
    int sub = tid & 7;
    int q8 = (sub & 1) * 8;
    int quarter = sub >> 1;
    int beg = offsets[g];
    int end = offsets[g + 1];
    int len = end - beg;
    int qlen = (len + 3) >> 2;
    int lo = beg + quarter * qlen;
    int hi = lo + qlen;
    if (lo > end) lo = end;
    if (hi > end) hi = end;
    float acc[8] = {0.f, 0.f, 0.f, 0.f, 0.f, 0.f, 0.f, 0.f};
    if (staged) {
        int i = lo - beg0;
        int hh = hi - beg0;
        for (; i + 4 <= hh; i += 4) {
            unsigned r0 = lrec[i];
            unsigned r1 = lrec[i + 1];
            unsigned r2 = lrec[i + 2];
            unsigned r3 = lrec[i + 3];
            int s0 = r0 & 0x1FFFF, s1 = r1 & 0x1FFFF, s2 = r2 & 0x1FFFF, s3 = r3 & 0x1FFFF;
            const half8 h0 = *reinterpret_cast<const half8*>(h + (size_t)s0 * NC + q8);
            const half8 h1 = *reinterpret_cast<const half8*>(h + (size_t)s1 * NC + q8);
            const half8 h2 = *reinterpret_cast<const half8*>(h + (size_t)s2 * NC + q8);
            const half8 h3 = *reinterpret_cast<const half8*>(h + (size_t)s3 * NC + q8);
            float w0 = hbits2f((unsigned short)(r0 >> 17));
            float w1 = hbits2f((unsigned short)(r1 >> 17));
            float w2 = hbits2f((unsigned short)(r2 >> 17));
            float w3 = hbits2f((unsigned short)(r3 >> 17));
#pragma unroll
            for (int j = 0; j < 8; ++j) {
                acc[j] += (float)h0[j] * w0 + (float)h1[j] * w1
                        + (float)h2[j] * w2 + (float)h3[j] * w3;
            }
        }
        for (; i < hh; ++i) {
            unsigned r0 = lrec[i];
            int s0 = r0 & 0x1FFFF;
            float w0 = hbits2f((unsigned short)(r0 >> 17));
            const half8 h0 = *reinterpret_cast<const half8*>(h + (size_t)s0 * NC + q8);
#pragma unroll
            for (int j = 0; j < 8; ++j) acc[j] += (float)h0[j] * w0;
        }
    } else {
        int i = lo;
        for (; i + 4 <= hi; i += 4) {
            unsigned r0 = __builtin_nontemporal_load(recs + i);
            unsigned r1 = __builtin_nontemporal_load(recs + i + 1);
            unsigned r2 = __builtin_nontemporal_load(recs + i + 2);
            unsigned r3 = __builtin_nontemporal_load(recs + i + 3);
            int s0 = r0 & 0x1FFFF, s1 = r1 & 0x1FFFF, s2 = r2 & 0x1FFFF, s3 = r3 & 0x1FFFF;
            const half8 h0 = *reinterpret_cast<const half8*>(h + (size_t)s0 * NC + q8);
            const half8 h1 = *reinterpret_cast<const half8*>(h + (size_t)s1 * NC + q8);
            const half8 h2 = *reinterpret_cast<const half8*>(h + (size_t)s2 * NC + q8);
            const half8 h3 = *reinterpret_cast<const half8*>(h + (size_t)s3 * NC + q8);
            float w0 = hbits2f((unsigned short)(r0 >> 17));
            float w1 = hbits2f((unsigned short)(r1 >> 17));
            float w2 = hbits2f((unsigned short)(r2 >> 17));
            float w3 = hbits2f((unsigned short)(r3 >> 17));
#pragma unroll
            for (int j = 0; j < 8; ++j) {
                acc[j] += (float)h0[j] * w0 + (float)h1[j] * w1
                        + (float)h2[j] * w2 + (float)h3[j] * w3;
            }
        }
        for (; i < hi; ++i) {
            unsigned r0 = __builtin_nontemporal_load(recs + i);
            int s0 = r0 & 0x1FFFF;
            float w0 = hbits2f((unsigned short)(r0 >> 17));
            const half8 h0 = *reinterpret_cast<const half8*>(h + (size_t)s0 * NC + q8);
#pragma unroll
            for (int j = 0; j < 8; ++j) acc[j] += (float)h0[j] * w0;
        }
    }
    // merge the 4 edge-quarters (lanes differ in bits 1-2 of sub)
#pragma unroll
    for (int j = 0; j < 8; ++j) {
        acc[j] += __shfl_xor(acc[j], 2);
        acc[j] += __shfl_xor(acc[j], 4);
    }
    float deg = degree[g];
    float d2 = deg * deg;
    const half8 hsv = *reinterpret_cast<const half8*>(h + (size_t)g * NC + q8);
    float v[8];
    float s8 = 0.f;
#pragma unroll
    for (int j = 0; j < 8; ++j) {
        v[j] = ALPHA_C * (float)hsv[j] + (1.f - ALPHA_C) * d2 * acc[j];
        s8 += v[j];
    }
    s8 += __shfl_xor(s8, 1);   // add the other class-half
    float inv = 1.f / s8;
#pragma unroll
    for (int j = 0; j < 8; ++j) v[j] *= inv;
    if (quarter == 0) {
        if (LAST) {
            float4 o0 = make_float4(v[0], v[1], v[2], v[3]);
            float4 o1 = make_float4(v[4], v[5], v[6], v[7]);
            *reinterpret_cast<float4*>(hout32 + (size_t)g * NC + q8) = o0;
            *reinterpret_cast<float4*>(hout32 + (size_t)g * NC + q8 + 4) = o1;
        } else {
            half8 o;
#pragma unroll
            for (int j = 0; j < 8; ++j) o[j] = (_Float16)v[j];
            *reinterpret_cast<half8*>(hout16 + (size_t)g * NC + q8) = o;
        }
    }
}

// ============ fallback (atomic-cursor CSR, fp32 gather) ============

__global__ void hist_kernel(const int* __restrict__ dst, int* __restrict__ counts) {
    int e = blockIdx.x * blockDim.x + threadIdx.x;
    if (e < NE) atomicAdd(&counts[dst[e]], 1);
}

__global__ void scatter_sort(const int* __restrict__ src, const int* __restrict__ dst,
                             const float* __restrict__ ew, const float* __restrict__ W,
                             const int* __restrict__ offsets, int* __restrict__ cursor,
                             int2* __restrict__ sorted) {
    int e = blockIdx.x * blockDim.x + threadIdx.x;
    if (e >= NE) return;
    int d = dst[e];
    int s = src[e];
    int pos = offsets[d] + atomicAdd(&cursor[d], 1);
    float w = ew[e] * W[s];
    sorted[pos] = make_int2(s, __float_as_int(w));
}

__global__ void gather1(const float* __restrict__ h, const int2* __restrict__ recs,
                        const int* __restrict__ offsets, const float* __restrict__ degree,
                        float* __restrict__ hout) {
    int t = blockIdx.x * blockDim.x + threadIdx.x;
    int g = t >> 2;
    int q = t & 3;
    if (g >= NN) return;
    int q4 = q * 4;
    int beg = offsets[g];
    int end = offsets[g + 1];
    float4 acc = make_float4(0.f, 0.f, 0.f, 0.f);
    for (int i = beg; i < end; ++i) {
        int2 r0 = recs[i];
        float w0 = __int_as_float(r0.y);
        const float4 h0 = *reinterpret_cast<const float4*>(h + (size_t)(r0.x & 0x1FFFF) * NC + q4);
        acc.x += h0.x * w0; acc.y += h0.y * w0; acc.z += h0.z * w0; acc.w += h0.w * w0;
    }
    float deg = degree[g];
    float d2 = deg * deg;
    const float4 hs = *reinterpret_cast<const float4*>(h + (size_t)g * NC + q4);
    float4 v;
    v.x = ALPHA_C * hs.x + (1.f - ALPHA_C) * d2 * acc.x;
    v.y = ALPHA_C * hs.y + (1.f - ALPHA_C) * d2 * acc.y;
    v.z = ALPHA_C * hs.z + (1.f - ALPHA_C) * d2 * acc.z;
    v.w = ALPHA_C * hs.w + (1.f - ALPHA_C) * d2 * acc.w;
    float s4 = v.x + v.y + v.z + v.w;
    s4 += __shfl_xor(s4, 1);
    s4 += __shfl_xor(s4, 2);
    float inv = 1.f / s4;
    v.x *= inv; v.y *= inv; v.z *= inv; v.w *= inv;
    *reinterpret_cast<float4*>(hout + (size_t)g * NC + q4) = v;
}

// ============ launch ============

extern "C" void kernel_launch(void* const* d_in, const int* in_sizes, int n_in,
                              void* d_out, int out_size, void* d_ws, size_t ws_size,
                              hipStream_t stream)
{
    const float* x      = (const float*)d_in[0];
    const float* W      = (const float*)d_in[1];
    const float* ew     = (const float*)d_in[2];
    const float* degree = (const float*)d_in[3];
    const int*   eidx   = (const int*)d_in[4];
    const int* src = eidx;
    const int* dst = eidx + NE;
    float* out = (float*)d_out;

    const int gather_blocks = NN / 32;                 // 3125, exact
    const int node_blocks4  = (NN * 4 + 255) / 256;
    const int edge_blocks   = (NE + 255) / 256;

    const size_t recs_elems   = (size_t)NE;            // int2 (build)
    const size_t recs4_elems  = (size_t)NE;            // u32 (gather)
    const size_t h16_elems    = (size_t)NN * NC;       // _Float16, x2 buffers
    const size_t counts_elems = (size_t)NBUK * NBLK + 1;
    const size_t off_elems    = (size_t)NN + 1;
    const size_t need = recs_elems * 8 + recs4_elems * 4 + h16_elems * 2 * 2
                      + counts_elems * 4 + off_elems * 4 + 1024 * 4 + 64;

    if (ws_size >= need) {
        int2*      recs      = (int2*)d_ws;
        unsigned*  recs4     = (unsigned*)(recs + recs_elems);
        _Float16*  h16a      = (_Float16*)(recs4 + recs4_elems);
        _Float16*  h16b      = h16a + h16_elems;
        int*       counts    = (int*)(h16b + h16_elems);
        int*       offsets   = counts + counts_elems;
        int*       blockSums = offsets + off_elems;

        bucket_count<<<NBLK, 1024, 0, stream>>>(dst, counts);
        const int n_scan = NBUK * NBLK;                 // 100096
        const int NB = (n_scan + 1023) / 1024;          // 98
        scanA<<<NB, 256, 0, stream>>>(counts, blockSums, n_scan);
        scanB<<<1, 1024, 0, stream>>>(blockSums, NB);
        scanC<<<(n_scan + 255) / 256, 256, 0, stream>>>(counts, blockSums, n_scan);
        bucket_scatter<<<NBLK, 1024, 0, stream>>>(src, dst, ew, W, counts, recs);
        bucket_sort<<<NBUK, 512, 0, stream>>>(recs, recs4, counts, offsets);

        f32_to_f16<<<(NN * NC / 4 + 255) / 256, 256, 0, stream>>>(x, h16a);
        gather_f16<false><<<gather_blocks, 256, 0, stream>>>(h16a, recs4, offsets, degree, h16b, nullptr);
        gather_f16<false><<<gather_blocks, 256, 0, stream>>>(h16b, recs4, offsets, degree, h16a, nullptr);
        gather_f16<false><<<gather_blocks, 256, 0, stream>>>(h16a, recs4, offsets, degree, h16b, nullptr);
        gather_f16<true ><<<gather_blocks, 256, 0, stream>>>(h16b, recs4, offsets, degree, nullptr, out);
        return;
    }

    // -------- fallback: single CSR with cursor atomics, fp32 gather --------
    {
        const size_t bufA_elems = (size_t)NN * NC;
        int2*  sorted    = (int2*)d_ws;
        float* bufA      = (float*)(sorted + NE);
        int*   offsets   = (int*)(bufA + bufA_elems);
        int*   cursor    = offsets + (NN + 1);
        int*   blockSums = cursor + NN;

        (void)hipMemsetAsync(offsets, 0, (size_t)(2 * NN + 1) * sizeof(int), stream);
        hist_kernel<<<edge_blocks, 256, 0, stream>>>(dst, offsets);
        const int NB = (NN + 1023) / 1024;
        scanA<<<NB, 256, 0, stream>>>(offsets, blockSums, NN);
        scanB<<<1, 1024, 0, stream>>>(blockSums, NB);
        scanC<<<(NN + 255) / 256, 256, 0, stream>>>(offsets, blockSums, NN);
        scatter_sort<<<edge_blocks, 256, 0, stream>>>(src, dst, ew, W, offsets, cursor, sorted);

        const float* hin = x;
        float* houts[NLAYERS] = {bufA, out, bufA, out};
        for (int l = 0; l < NLAYERS; ++l) {
            gather1<<<node_blocks4, 256, 0, stream>>>(hin, sorted, offsets, degree, houts[l]);
            hin = houts[l];
        }
    }
}

// Round 18
// 149.211 us; speedup vs baseline: 2.1457x; 1.0153x over previous
//
#include <hip/hip_runtime.h>

#define NN 100000
#define NC 16
#define NE 3200000
#define NLAYERS 4
#define ALPHA_C 0.5f

#define BSHIFT 8
#define NBUK 391            // ceil(NN / 256)
#define EPB 12544           // edges per block -> exactly 256 blocks
#define NBLK 256
#define CAP 12288           // bucket_sort LDS staging (mean 8192, +45 sigma)
#define LCAP 4096           // gather LDS rec window (mean 1024, +96 sigma)

typedef __attribute__((ext_vector_type(4))) _Float16 half4;
typedef __attribute__((ext_vector_type(8))) _Float16 half8;

static __device__ __forceinline__ unsigned short f2h_bits(float w) {
    _Float16 h = (_Float16)w;
    unsigned short b;
    __builtin_memcpy(&b, &h, 2);
    return b;
}
static __device__ __forceinline__ float hbits2f(unsigned short b) {
    _Float16 h;
    __builtin_memcpy(&h, &b, 2);
    return (float)h;
}

// ============ build phase (LDS atomics only) ============

// Histogram of coarse buckets + fused f32->f16 conversion of x (tail work).
__global__ __launch_bounds__(1024) void bucket_count(const int* __restrict__ dst,
                                                     int* __restrict__ counts,
                                                     const float* __restrict__ x,
                                                     _Float16* __restrict__ h16) {
    __shared__ int h[NBUK];
    for (int i = threadIdx.x; i < NBUK; i += 1024) h[i] = 0;
    __syncthreads();
    int base = blockIdx.x * EPB;
    int nedge = min(EPB, NE - base);
    for (int i = threadIdx.x; i < nedge; i += 1024)
        atomicAdd(&h[dst[base + i] >> BSHIFT], 1);
    __syncthreads();
    for (int i = threadIdx.x; i < NBUK; i += 1024)
        counts[i * NBLK + blockIdx.x] = h[i];   // bucket-major for the scan
    // fused conversion: 400000 float4-groups over 262144 threads
    for (int i = blockIdx.x * 1024 + threadIdx.x; i < NN * NC / 4; i += NBLK * 1024) {
        float4 v = *reinterpret_cast<const float4*>(x + i * 4);
        half4 o;
        o.x = (_Float16)v.x; o.y = (_Float16)v.y;
        o.z = (_Float16)v.z; o.w = (_Float16)v.w;
        *reinterpret_cast<half4*>(h16 + i * 4) = o;
    }
}

// Exclusive scan, 1024 elements per block (256 threads x 4 elems).
__global__ void scanA(int* __restrict__ data, int* __restrict__ blockSums, int n) {
    __shared__ int lds[256];
    int base = blockIdx.x * 1024 + threadIdx.x * 4;
    int v[4] = {0, 0, 0, 0};
#pragma unroll
    for (int i = 0; i < 4; ++i) { int idx = base + i; if (idx < n) v[i] = data[idx]; }
    int tsum = v[0] + v[1] + v[2] + v[3];
    lds[threadIdx.x] = tsum;
    __syncthreads();
    for (int off = 1; off < 256; off <<= 1) {
        int t = (threadIdx.x >= off) ? lds[threadIdx.x - off] : 0;
        __syncthreads();
        lds[threadIdx.x] += t;
        __syncthreads();
    }
    if (threadIdx.x == 255) blockSums[blockIdx.x] = lds[255];
    int run = lds[threadIdx.x] - tsum;
#pragma unroll
    for (int i = 0; i < 4; ++i) {
        int idx = base + i;
        if (idx < n) { int old = v[i]; data[idx] = run; run += old; }
    }
}

__global__ void scanB(int* __restrict__ blockSums, int nb) {
    __shared__ int lds[1024];
    int t = threadIdx.x;
    lds[t] = (t < nb) ? blockSums[t] : 0;
    __syncthreads();
    for (int off = 1; off < 1024; off <<= 1) {
        int v = (t >= off) ? lds[t - off] : 0;
        __syncthreads();
        lds[t] += v;
        __syncthreads();
    }
    if (t < nb) blockSums[t] = (t == 0) ? 0 : lds[t - 1];
}

// LDS-staged scatter: histogram -> LDS scan -> LDS placement (bucket-ordered)
// -> linear coalesced write-out of PACKED 4B payload (src|fp16w<<17) + 1B
// local-dst stream. Global scanned value = counts[] + blockSums[>>10] inline.
__global__ __launch_bounds__(1024) void bucket_scatter(
        const int* __restrict__ src, const int* __restrict__ dst,
        const float* __restrict__ ew, const float* __restrict__ W,
        const int* __restrict__ counts, const int* __restrict__ blockSums,
        unsigned* __restrict__ payload4, unsigned char* __restrict__ lbid1) {
    __shared__ unsigned lpay[EPB];           // 50176 B
    __shared__ unsigned short lbid[EPB];     // 25088 B
    __shared__ unsigned char ldst[EPB];      // 12544 B
    __shared__ int h[NBUK];
    __shared__ int lbase[NBUK];
    __shared__ int delta[NBUK];
    __shared__ int sc[512];
    int t = threadIdx.x;
    int blk = blockIdx.x;
    for (int i = t; i < NBUK; i += 1024) h[i] = 0;
    __syncthreads();
    int base = blk * EPB;
    int nedge = min(EPB, NE - base);
    for (int i = t; i < nedge; i += 1024)
        atomicAdd(&h[dst[base + i] >> BSHIFT], 1);
    __syncthreads();
    // exclusive LDS scan of h -> lbase; delta = global base - local base
    if (t < 512) sc[t] = (t < NBUK) ? h[t] : 0;
    __syncthreads();
    for (int off = 1; off < 512; off <<= 1) {
        int v = (t >= off && t < 512) ? sc[t - off] : 0;
        __syncthreads();
        if (t < 512) sc[t] += v;
        __syncthreads();
    }
    if (t < NBUK) {
        int excl = sc[t] - h[t];
        lbase[t] = excl;
        int gidx = t * NBLK + blk;
        delta[t] = counts[gidx] + blockSums[gidx >> 10] - excl;
        h[t] = 0;
    }
    __syncthreads();
    // placement into LDS, bucket-ordered; pack final 4B record here
    for (int i = t; i < nedge; i += 1024) {
        int e = base + i;
        int d = dst[e];
        int s = src[e];
        float w = ew[e] * W[s];
        int b = d >> BSHIFT;
        int r = atomicAdd(&h[b], 1);
        int slot = lbase[b] + r;
        unsigned short hb = f2h_bits(w);
        lpay[slot] = (unsigned)s | ((unsigned)hb << 17);
        lbid[slot] = (unsigned short)b;
        ldst[slot] = (unsigned char)(d & 255);
    }
    __syncthreads();
    // coalesced write-out: consecutive threads -> consecutive addresses per run
    for (int i = t; i < nedge; i += 1024) {
        int b = lbid[i];
        int pos = i + delta[b];
        payload4[pos] = lpay[i];
        lbid1[pos] = ldst[i];
    }
}

// One block (512 thr) per bucket: stage 4B payload + 1B local-dst in LDS,
// counting-sort the 256 local dsts, write CSR offsets + dst-sorted recs4.
__global__ void bucket_sort(const unsigned* __restrict__ payload4,
                            const unsigned char* __restrict__ lbid1,
                            unsigned* __restrict__ recs4,
                            const int* __restrict__ counts,
                            const int* __restrict__ blockSums,
                            int* __restrict__ offsets) {
    __shared__ unsigned lpay[CAP];           // 49152 B
    __shared__ unsigned char lld[CAP];       // 12288 B
    __shared__ int hcnt[256];
    __shared__ int hscan[256];
    __shared__ int hexcl[256];
    int b = blockIdx.x;
    int t = threadIdx.x;
    int i0 = b * NBLK;
    int beg = counts[i0] + blockSums[i0 >> 10];
    int end;
    if (b == NBUK - 1) end = NE;
    else {
        int i1 = (b + 1) * NBLK;
        end = counts[i1] + blockSums[i1 >> 10];
    }
    int cnt = end - beg;
    if (t < 256) hcnt[t] = 0;
    __syncthreads();
    for (int i = t; i < cnt && i < CAP; i += 512) {
        lpay[i] = payload4[beg + i];
        int ld = lbid1[beg + i];
        lld[i] = (unsigned char)ld;
        atomicAdd(&hcnt[ld], 1);
    }
    __syncthreads();
    if (t < 256) hscan[t] = hcnt[t];
    __syncthreads();
    for (int off = 1; off < 256; off <<= 1) {
        int v = 0;
        if (t >= off && t < 256) v = hscan[t - off];
        __syncthreads();
        if (t < 256) hscan[t] += v;
        __syncthreads();
    }
    if (t < 256) {
        hexcl[t] = hscan[t] - hcnt[t];
        int d = (b << BSHIFT) + t;
        if (d < NN) offsets[d] = beg + hexcl[t];
        hcnt[t] = 0;
    }
    if (b == NBUK - 1 && t == 0) offsets[NN] = NE;
    __syncthreads();
    for (int i = t; i < cnt && i < CAP; i += 512) {
        int ld = lld[i];
        int r = atomicAdd(&hcnt[ld], 1);
        recs4[beg + hexcl[ld] + r] = lpay[i];
    }
}

// ============ per-layer gather (fp16 h, packed 4B recs staged in LDS, 8 lanes/node) ============
// Block = 256 thr = 32 nodes. The block's contiguous ~1K-rec CSR window is
// staged into 16KB LDS (coalesced); per-lane loops read recs from LDS.
// 16.4KB LDS + launch_bounds(256,8) -> 8 blocks/CU = 32 waves (max occupancy).
// sub = t&7: q = sub&1 owns classes [8q,8q+8); quarter = sub>>1 owns an edge
// quarter. Quarters merged via shfl_xor(2,4); rownorm via shfl_xor(1).
template<bool LAST>
__global__ __launch_bounds__(256, 8) void gather_f16(
        const _Float16* __restrict__ h, const unsigned* __restrict__ recs,
        const int* __restrict__ offsets, const float* __restrict__ degree,
        _Float16* __restrict__ hout16, float* __restrict__ hout32) {
    __shared__ unsigned lrec[LCAP];
    __shared__ int srange[2];
    int tid = threadIdx.x;
    int gfirst = blockIdx.x * 32;
    if (tid < 2) srange[tid] = offsets[gfirst + tid * 32];
    __syncthreads();
    int beg0 = srange[0];
    int n0 = srange[1] - beg0;
    bool staged = (n0 <= LCAP);
    if (staged) {
        for (int i = tid; i < n0; i += 256)
            lrec[i] = recs[beg0 + i];    // coalesced
    }
    __syncthreads();
    int g = gfirst + (tid >> 3);
    int sub = tid & 7;
    int q8 = (sub & 1) * 8;
    int quarter = sub >> 1;
    int beg = offsets[g];
    int end = offsets[g + 1];
    int len = end - beg;
    int qlen = (len + 3) >> 2;
    int lo = beg + quarter * qlen;
    int hi = lo + qlen;
    if (lo > end) lo = end;
    if (hi > end) hi = end;
    float acc[8] = {0.f, 0.f, 0.f, 0.f, 0.f, 0.f, 0.f, 0.f};
    if (staged) {
        int i = lo - beg0;
        int hh = hi - beg0;
        for (; i + 4 <= hh; i += 4) {
            unsigned r0 = lrec[i];
            unsigned r1 = lrec[i + 1];
            unsigned r2 = lrec[i + 2];
            unsigned r3 = lrec[i + 3];
            int s0 = r0 & 0x1FFFF, s1 = r1 & 0x1FFFF, s2 = r2 & 0x1FFFF, s3 = r3 & 0x1FFFF;
            const half8 h0 = *reinterpret_cast<const half8*>(h + (size_t)s0 * NC + q8);
            const half8 h1 = *reinterpret_cast<const half8*>(h + (size_t)s1 * NC + q8);
            const half8 h2 = *reinterpret_cast<const half8*>(h + (size_t)s2 * NC + q8);
            const half8 h3 = *reinterpret_cast<const half8*>(h + (size_t)s3 * NC + q8);
            float w0 = hbits2f((unsigned short)(r0 >> 17));
            float w1 = hbits2f((unsigned short)(r1 >> 17));
            float w2 = hbits2f((unsigned short)(r2 >> 17));
            float w3 = hbits2f((unsigned short)(r3 >> 17));
#pragma unroll
            for (int j = 0; j < 8; ++j) {
                acc[j] += (float)h0[j] * w0 + (float)h1[j] * w1
                        + (float)h2[j] * w2 + (float)h3[j] * w3;
            }
        }
        for (; i < hh; ++i) {
            unsigned r0 = lrec[i];
            int s0 = r0 & 0x1FFFF;
            float w0 = hbits2f((unsigned short)(r0 >> 17));
            const half8 h0 = *reinterpret_cast<const half8*>(h + (size_t)s0 * NC + q8);
#pragma unroll
            for (int j = 0; j < 8; ++j) acc[j] += (float)h0[j] * w0;
        }
    } else {
        int i = lo;
        for (; i + 4 <= hi; i += 4) {
            unsigned r0 = __builtin_nontemporal_load(recs + i);
            unsigned r1 = __builtin_nontemporal_load(recs + i + 1);
            unsigned r2 = __builtin_nontemporal_load(recs + i + 2);
            unsigned r3 = __builtin_nontemporal_load(recs + i + 3);
            int s0 = r0 & 0x1FFFF, s1 = r1 & 0x1FFFF, s2 = r2 & 0x1FFFF, s3 = r3 & 0x1FFFF;
            const half8 h0 = *reinterpret_cast<const half8*>(h + (size_t)s0 * NC + q8);
            const half8 h1 = *reinterpret_cast<const half8*>(h + (size_t)s1 * NC + q8);
            const half8 h2 = *reinterpret_cast<const half8*>(h + (size_t)s2 * NC + q8);
            const half8 h3 = *reinterpret_cast<const half8*>(h + (size_t)s3 * NC + q8);
            float w0 = hbits2f((unsigned short)(r0 >> 17));
            float w1 = hbits2f((unsigned short)(r1 >> 17));
            float w2 = hbits2f((unsigned short)(r2 >> 17));
            float w3 = hbits2f((unsigned short)(r3 >> 17));
#pragma unroll
            for (int j = 0; j < 8; ++j) {
                acc[j] += (float)h0[j] * w0 + (float)h1[j] * w1
                        + (float)h2[j] * w2 + (float)h3[j] * w3;
            }
        }
        for (; i < hi; ++i) {
            unsigned r0 = __builtin_nontemporal_load(recs + i);
            int s0 = r0 & 0x1FFFF;
            float w0 = hbits2f((unsigned short)(r0 >> 17));
            const half8 h0 = *reinterpret_cast<const half8*>(h + (size_t)s0 * NC + q8);
#pragma unroll
            for (int j = 0; j < 8; ++j) acc[j] += (float)h0[j] * w0;
        }
    }
    // merge the 4 edge-quarters (lanes differ in bits 1-2 of sub)
#pragma unroll
    for (int j = 0; j < 8; ++j) {
        acc[j] += __shfl_xor(acc[j], 2);
        acc[j] += __shfl_xor(acc[j], 4);
    }
    float deg = degree[g];
    float d2 = deg * deg;
    const half8 hsv = *reinterpret_cast<const half8*>(h + (size_t)g * NC + q8);
    float v[8];
    float s8 = 0.f;
#pragma unroll
    for (int j = 0; j < 8; ++j) {
        v[j] = ALPHA_C * (float)hsv[j] + (1.f - ALPHA_C) * d2 * acc[j];
        s8 += v[j];
    }
    s8 += __shfl_xor(s8, 1);   // add the other class-half
    float inv = 1.f / s8;
#pragma unroll
    for (int j = 0; j < 8; ++j) v[j] *= inv;
    if (quarter == 0) {
        if (LAST) {
            float4 o0 = make_float4(v[0], v[1], v[2], v[3]);
            float4 o1 = make_float4(v[4], v[5], v[6], v[7]);
            *reinterpret_cast<float4*>(hout32 + (size_t)g * NC + q8) = o0;
            *reinterpret_cast<float4*>(hout32 + (size_t)g * NC + q8 + 4) = o1;
        } else {
            half8 o;
#pragma unroll
            for (int j = 0; j < 8; ++j) o[j] = (_Float16)v[j];
            *reinterpret_cast<half8*>(hout16 + (size_t)g * NC + q8) = o;
        }
    }
}

// ============ fallback (atomic-cursor CSR, fp32 gather) ============

__global__ void hist_kernel(const int* __restrict__ dst, int* __restrict__ counts) {
    int e = blockIdx.x * blockDim.x + threadIdx.x;
    if (e < NE) atomicAdd(&counts[dst[e]], 1);
}

__global__ void scanC_fb(int* __restrict__ data, const int* __restrict__ blockSums, int n) {
    int idx = blockIdx.x * blockDim.x + threadIdx.x;
    if (idx < n) data[idx] += blockSums[idx >> 10];
    if (idx == 0) data[n] = NE;
}

__global__ void scatter_sort(const int* __restrict__ src, const int* __restrict__ dst,
                             const float* __restrict__ ew, const float* __restrict__ W,
                             const int* __restrict__ offsets, int* __restrict__ cursor,
                             int2* __restrict__ sorted) {
    int e = blockIdx.x * blockDim.x + threadIdx.x;
    if (e >= NE) return;
    int d = dst[e];
    int s = src[e];
    int pos = offsets[d] + atomicAdd(&cursor[d], 1);
    float w = ew[e] * W[s];
    sorted[pos] = make_int2(s, __float_as_int(w));
}

__global__ void gather1(const float* __restrict__ h, const int2* __restrict__ recs,
                        const int* __restrict__ offsets, const float* __restrict__ degree,
                        float* __restrict__ hout) {
    int t = blockIdx.x * blockDim.x + threadIdx.x;
    int g = t >> 2;
    int q = t & 3;
    if (g >= NN) return;
    int q4 = q * 4;
    int beg = offsets[g];
    int end = offsets[g + 1];
    float4 acc = make_float4(0.f, 0.f, 0.f, 0.f);
    for (int i = beg; i < end; ++i) {
        int2 r0 = recs[i];
        float w0 = __int_as_float(r0.y);
        const float4 h0 = *reinterpret_cast<const float4*>(h + (size_t)(r0.x & 0x1FFFF) * NC + q4);
        acc.x += h0.x * w0; acc.y += h0.y * w0; acc.z += h0.z * w0; acc.w += h0.w * w0;
    }
    float deg = degree[g];
    float d2 = deg * deg;
    const float4 hs = *reinterpret_cast<const float4*>(h + (size_t)g * NC + q4);
    float4 v;
    v.x = ALPHA_C * hs.x + (1.f - ALPHA_C) * d2 * acc.x;
    v.y = ALPHA_C * hs.y + (1.f - ALPHA_C) * d2 * acc.y;
    v.z = ALPHA_C * hs.z + (1.f - ALPHA_C) * d2 * acc.z;
    v.w = ALPHA_C * hs.w + (1.f - ALPHA_C) * d2 * acc.w;
    float s4 = v.x + v.y + v.z + v.w;
    s4 += __shfl_xor(s4, 1);
    s4 += __shfl_xor(s4, 2);
    float inv = 1.f / s4;
    v.x *= inv; v.y *= inv; v.z *= inv; v.w *= inv;
    *reinterpret_cast<float4*>(hout + (size_t)g * NC + q4) = v;
}

// ============ launch ============

extern "C" void kernel_launch(void* const* d_in, const int* in_sizes, int n_in,
                              void* d_out, int out_size, void* d_ws, size_t ws_size,
                              hipStream_t stream)
{
    const float* x      = (const float*)d_in[0];
    const float* W      = (const float*)d_in[1];
    const float* ew     = (const float*)d_in[2];
    const float* degree = (const float*)d_in[3];
    const int*   eidx   = (const int*)d_in[4];
    const int* src = eidx;
    const int* dst = eidx + NE;
    float* out = (float*)d_out;

    const int gather_blocks = NN / 32;                 // 3125, exact
    const int node_blocks4  = (NN * 4 + 255) / 256;
    const int edge_blocks   = (NE + 255) / 256;

    const size_t pay_elems    = (size_t)NE;            // u32
    const size_t lbid_bytes   = (size_t)NE;            // u8
    const size_t recs4_elems  = (size_t)NE;            // u32
    const size_t h16_elems    = (size_t)NN * NC;       // _Float16, x2 buffers
    const size_t counts_elems = (size_t)NBUK * NBLK + 1;
    const size_t off_elems    = (size_t)NN + 1;
    const size_t need = pay_elems * 4 + lbid_bytes + recs4_elems * 4
                      + h16_elems * 2 * 2 + counts_elems * 4 + off_elems * 4
                      + 1024 * 4 + 128;

    if (ws_size >= need) {
        unsigned*      payload4  = (unsigned*)d_ws;
        unsigned*      recs4     = payload4 + pay_elems;
        _Float16*      h16a      = (_Float16*)(recs4 + recs4_elems);
        _Float16*      h16b      = h16a + h16_elems;
        unsigned char* lbid1     = (unsigned char*)(h16b + h16_elems);
        int*           counts    = (int*)(lbid1 + lbid_bytes);
        int*           offsets   = counts + counts_elems;
        int*           blockSums = offsets + off_elems;

        bucket_count<<<NBLK, 1024, 0, stream>>>(dst, counts, x, h16a);
        const int n_scan = NBUK * NBLK;                 // 100096
        const int NB = (n_scan + 1023) / 1024;          // 98
        scanA<<<NB, 256, 0, stream>>>(counts, blockSums, n_scan);
        scanB<<<1, 1024, 0, stream>>>(blockSums, NB);
        bucket_scatter<<<NBLK, 1024, 0, stream>>>(src, dst, ew, W, counts, blockSums,
                                                  payload4, lbid1);
        bucket_sort<<<NBUK, 512, 0, stream>>>(payload4, lbid1, recs4, counts,
                                              blockSums, offsets);

        gather_f16<false><<<gather_blocks, 256, 0, stream>>>(h16a, recs4, offsets, degree, h16b, nullptr);
        gather_f16<false><<<gather_blocks, 256, 0, stream>>>(h16b, recs4, offsets, degree, h16a, nullptr);
        gather_f16<false><<<gather_blocks, 256, 0, stream>>>(h16a, recs4, offsets, degree, h16b, nullptr);
        gather_f16<true ><<<gather_blocks, 256, 0, stream>>>(h16b, recs4, offsets, degree, nullptr, out);
        return;
    }

    // -------- fallback: single CSR with cursor atomics, fp32 gather --------
    {
        const size_t bufA_elems = (size_t)NN * NC;
        int2*  sorted    = (int2*)d_ws;
        float* bufA      = (float*)(sorted + NE);
        int*   offsets   = (int*)(bufA + bufA_elems);
        int*   cursor    = offsets + (NN + 1);
        int*   blockSums = cursor + NN;

        (void)hipMemsetAsync(offsets, 0, (size_t)(2 * NN + 1) * sizeof(int), stream);
        hist_kernel<<<edge_blocks, 256, 0, stream>>>(dst, offsets);
        const int NB = (NN + 1023) / 1024;
        scanA<<<NB, 256, 0, stream>>>(offsets, blockSums, NN);
        scanB<<<1, 1024, 0, stream>>>(blockSums, NB);
        scanC_fb<<<(NN + 255) / 256, 256, 0, stream>>>(offsets, blockSums, NN);
        scatter_sort<<<edge_blocks, 256, 0, stream>>>(src, dst, ew, W, offsets, cursor, sorted);

        const float* hin = x;
        float* houts[NLAYERS] = {bufA, out, bufA, out};
        for (int l = 0; l < NLAYERS; ++l) {
            gather1<<<node_blocks4, 256, 0, stream>>>(hin, sorted, offsets, degree, houts[l]);
            hin = houts[l];
        }
    }
}